// Round 1
// baseline (2716.123 us; speedup 1.0000x reference)
//
#include <hip/hip_runtime.h>
#include <hip/hip_bf16.h>

#define NN 10000
#define EE 160000
#define LL 6

#define INV_SQRT_3f  0.57735026919f
#define INV_SQRT_Hf  0.08838834764832f
#define INV_SQRT_2f  0.70710678118655f

__device__ __forceinline__ float ssilu_f(float v){
  float s = 1.0f / (1.0f + __expf(-v));
  return v * s * 1.6666666666667f;
}
__device__ __forceinline__ float bcast(float v, int l){
  return __int_as_float(__builtin_amdgcn_readlane(__float_as_int(v), l));
}

// ---------------- xh = ssilu(lnorm(x)@xp1+b)@xp2+b   (16 nodes / 256-thr block)
__global__ __launch_bounds__(256) void k_xh(
    const float* __restrict__ x,
    const float* __restrict__ lnw, const float* __restrict__ lnb,
    const float* __restrict__ w1, const float* __restrict__ b1,
    const float* __restrict__ w2, const float* __restrict__ b2,
    float* __restrict__ xh)
{
  __shared__ __align__(16) float s_xn[16][128];
  __shared__ __align__(16) float s_h1[16][128];
  int t = threadIdx.x;
  int n0 = blockIdx.x * 16;
  {
    int r = t >> 4, cc = t & 15;
    const float* xr = x + (size_t)(n0 + r) * 128;
    float v[8];
    float s = 0.f, ss = 0.f;
    #pragma unroll
    for (int u = 0; u < 8; u++){
      v[u] = xr[cc + 16*u];
      s += v[u]; ss += v[u]*v[u];
    }
    #pragma unroll
    for (int off = 8; off > 0; off >>= 1){
      s  += __shfl_xor(s, off, 16);
      ss += __shfl_xor(ss, off, 16);
    }
    float mean = s * (1.0f/128.0f);
    float var  = ss * (1.0f/128.0f) - mean*mean;
    float rstd = rsqrtf(var + 1e-5f);
    #pragma unroll
    for (int u = 0; u < 8; u++){
      int h = cc + 16*u;
      s_xn[r][h] = (v[u] - mean) * rstd * lnw[h] + lnb[h];
    }
  }
  __syncthreads();
  {
    int c = t & 127;
    int rb = t >> 7;
    float acc[8];
    float bv = b1[c];
    #pragma unroll
    for (int u = 0; u < 8; u++) acc[u] = bv;
    for (int k = 0; k < 128; k += 4){
      float w0 = w1[(k+0)*128 + c];
      float wq = w1[(k+1)*128 + c];
      float wz = w1[(k+2)*128 + c];
      float ww = w1[(k+3)*128 + c];
      #pragma unroll
      for (int u = 0; u < 8; u++){
        float4 xv = *(const float4*)&s_xn[rb + 2*u][k];
        acc[u] = fmaf(xv.x, w0, acc[u]);
        acc[u] = fmaf(xv.y, wq, acc[u]);
        acc[u] = fmaf(xv.z, wz, acc[u]);
        acc[u] = fmaf(xv.w, ww, acc[u]);
      }
    }
    #pragma unroll
    for (int u = 0; u < 8; u++) s_h1[rb + 2*u][c] = ssilu_f(acc[u]);
  }
  __syncthreads();
  {
    int c = t & 127;
    int rb = t >> 7;
    float a0[8], a1[8], a2[8];
    float bb0 = b2[c], bb1 = b2[c+128], bb2 = b2[c+256];
    #pragma unroll
    for (int u=0;u<8;u++){ a0[u]=bb0; a1[u]=bb1; a2[u]=bb2; }
    for (int k = 0; k < 128; k += 4){
      float wa[4], wb[4], wc[4];
      #pragma unroll
      for (int j=0;j<4;j++){
        const float* wr = w2 + (size_t)(k+j)*384;
        wa[j]=wr[c]; wb[j]=wr[c+128]; wc[j]=wr[c+256];
      }
      #pragma unroll
      for (int u = 0; u < 8; u++){
        float4 hv = *(const float4*)&s_h1[rb + 2*u][k];
        a0[u]=fmaf(hv.x,wa[0],a0[u]); a0[u]=fmaf(hv.y,wa[1],a0[u]); a0[u]=fmaf(hv.z,wa[2],a0[u]); a0[u]=fmaf(hv.w,wa[3],a0[u]);
        a1[u]=fmaf(hv.x,wb[0],a1[u]); a1[u]=fmaf(hv.y,wb[1],a1[u]); a1[u]=fmaf(hv.z,wb[2],a1[u]); a1[u]=fmaf(hv.w,wb[3],a1[u]);
        a2[u]=fmaf(hv.x,wc[0],a2[u]); a2[u]=fmaf(hv.y,wc[1],a2[u]); a2[u]=fmaf(hv.z,wc[2],a2[u]); a2[u]=fmaf(hv.w,wc[3],a2[u]);
      }
    }
    #pragma unroll
    for (int u = 0; u < 8; u++){
      float* o = xh + (size_t)(n0 + rb + 2*u) * 384;
      o[c] = a0[u]; o[c+128] = a1[u]; o[c+256] = a2[u];
    }
  }
}

// ---------------- edge kernel: rbfh GEMV + gather + atomic scatter
__global__ __launch_bounds__(512) void k_edge(
    const float* __restrict__ erbf, const float* __restrict__ rbf_w, const float* __restrict__ rbf_b,
    const int* __restrict__ esrc, const int* __restrict__ edst,
    const float* __restrict__ evec,
    const float* __restrict__ xh, const float* __restrict__ vec,
    float* __restrict__ dx, float* __restrict__ dvec)
{
  __shared__ __hip_bfloat16 wlds[64*384];
  int t = threadIdx.x;
  for (int i = t; i < 64*384; i += 512) wlds[i] = __float2bfloat16(rbf_w[i]);
  __syncthreads();
  int lane = t & 63;
  int wid = (blockIdx.x * 512 + t) >> 6;
  int nw = gridDim.x * 8;
  float bias[6];
  #pragma unroll
  for (int j = 0; j < 6; j++) bias[j] = rbf_b[lane + 64*j];
  for (int g = wid; g < EE/8; g += nw){
    int e0 = g * 8;
    float rv[8];
    #pragma unroll
    for (int e = 0; e < 8; e++) rv[e] = erbf[(e0+e)*64 + lane];
    float acc[8][6];
    #pragma unroll
    for (int e = 0; e < 8; e++){
      #pragma unroll
      for (int j = 0; j < 6; j++) acc[e][j] = bias[j];
    }
    #pragma unroll 2
    for (int r = 0; r < 64; r++){
      const __hip_bfloat16* wr = &wlds[r*384 + lane];
      float w[6];
      #pragma unroll
      for (int j = 0; j < 6; j++) w[j] = __bfloat162float(wr[64*j]);
      #pragma unroll
      for (int e = 0; e < 8; e++){
        float bv = bcast(rv[e], r);
        #pragma unroll
        for (int j = 0; j < 6; j++) acc[e][j] = fmaf(bv, w[j], acc[e][j]);
      }
    }
    #pragma unroll 1
    for (int e = 0; e < 8; e++){
      int sN = esrc[e0+e], dN = edst[e0+e];
      const float* xr = xh + (size_t)sN * 384;
      float m0  = acc[e][0] * xr[lane];
      float m1  = acc[e][1] * xr[64+lane];
      float m2a = acc[e][2] * xr[128+lane] * INV_SQRT_3f;
      float m2b = acc[e][3] * xr[192+lane] * INV_SQRT_3f;
      float m3a = acc[e][4] * xr[256+lane];
      float m3b = acc[e][5] * xr[320+lane];
      float* dxr = dx + (size_t)dN * 128;
      atomicAdd(dxr + lane, m0);
      atomicAdd(dxr + 64 + lane, m1);
      const float* vr = vec + (size_t)sN * 384;
      float* dvr = dvec + (size_t)dN * 384;
      #pragma unroll
      for (int cd = 0; cd < 3; cd++){
        float ev = evec[(e0+e)*3 + cd];
        float va = vr[cd*128 + lane];
        float vb = vr[cd*128 + 64 + lane];
        atomicAdd(dvr + cd*128 + lane,      (va*m2a + m3a*ev) * INV_SQRT_Hf);
        atomicAdd(dvr + cd*128 + 64 + lane, (vb*m2b + m3b*ev) * INV_SQRT_Hf);
      }
    }
  }
}

// ---------------- node update: x,vec += agg; vp; vec_dot/vnorm; xv MLP; final (8 nodes/block)
__global__ __launch_bounds__(256) void k_node(
    const float* __restrict__ vp_w,
    const float* __restrict__ xv1_w, const float* __restrict__ xv1_b,
    const float* __restrict__ xv2_w, const float* __restrict__ xv2_b,
    const float* __restrict__ dx, const float* __restrict__ dvec,
    float* __restrict__ x, float* __restrict__ vec)
{
  __shared__ __align__(16) float s_xn[8][128];
  __shared__ __align__(16) float s_vl[8][384];
  __shared__ __align__(16) float s_v1[8][384];
  __shared__ __align__(16) float s_v2[8][384];   // reused as g output later
  __shared__ __align__(16) float s_vd[8][128];
  __shared__ __align__(16) float s_vn[8][128];
  __shared__ __align__(16) float s_h1[8][128];
  int t = threadIdx.x;
  int n0 = blockIdx.x * 8;
  for (int idx = t; idx < 8*128; idx += 256){
    int i = idx >> 7, h = idx & 127;
    size_t p = (size_t)(n0+i)*128 + h;
    s_xn[i][h] = (x[p] + dx[p]) * INV_SQRT_2f;
  }
  for (int idx = t; idx < 8*384; idx += 256){
    int i = idx / 384, h = idx % 384;
    size_t p = (size_t)(n0+i)*384 + h;
    s_vl[i][h] = vec[p] + dvec[p];
  }
  __syncthreads();
  // vp = vl @ vp_w (128x256) -> v1|v2
  {
    int ob = t & 127;
    int ib = (t >> 7) * 4;
    float acc0[4][3], acc1[4][3];
    #pragma unroll
    for (int ii=0;ii<4;ii++){
      #pragma unroll
      for (int cd=0;cd<3;cd++){ acc0[ii][cd]=0.f; acc1[ii][cd]=0.f; }
    }
    for (int k = 0; k < 128; k += 4){
      float wA[4], wB[4];
      #pragma unroll
      for (int j=0;j<4;j++){
        const float* wr = vp_w + (size_t)(k+j)*256;
        wA[j] = wr[ob]; wB[j] = wr[ob+128];
      }
      #pragma unroll
      for (int ii = 0; ii < 4; ii++){
        #pragma unroll
        for (int cd = 0; cd < 3; cd++){
          float4 a = *(const float4*)&s_vl[ib+ii][cd*128 + k];
          float s0 = acc0[ii][cd], s1 = acc1[ii][cd];
          s0 = fmaf(a.x, wA[0], s0); s0 = fmaf(a.y, wA[1], s0); s0 = fmaf(a.z, wA[2], s0); s0 = fmaf(a.w, wA[3], s0);
          s1 = fmaf(a.x, wB[0], s1); s1 = fmaf(a.y, wB[1], s1); s1 = fmaf(a.z, wB[2], s1); s1 = fmaf(a.w, wB[3], s1);
          acc0[ii][cd] = s0; acc1[ii][cd] = s1;
        }
      }
    }
    #pragma unroll
    for (int ii = 0; ii < 4; ii++){
      #pragma unroll
      for (int cd = 0; cd < 3; cd++){
        s_v1[ib+ii][cd*128 + ob] = acc0[ii][cd];
        s_v2[ib+ii][cd*128 + ob] = acc1[ii][cd];
      }
    }
  }
  __syncthreads();
  #pragma unroll
  for (int rep = 0; rep < 4; rep++){
    int idx = rep*256 + t;
    int i = idx >> 7, h = idx & 127;
    float a0 = s_v1[i][h],     b0 = s_v2[i][h];
    float a1 = s_v1[i][128+h], b1 = s_v2[i][128+h];
    float a2 = s_v1[i][256+h], b2 = s_v2[i][256+h];
    s_vd[i][h] = (a0*b0 + a1*b1 + a2*b2) * INV_SQRT_Hf;
    s_vn[i][h] = sqrtf(b0*b0 + b1*b1 + b2*b2 + 1e-8f);
  }
  __syncthreads();
  // h1 = ssilu(cat(xn, vn) @ xv1_w + b)
  {
    int c = t & 127;
    int ib = (t >> 7) * 4;
    float acc[4];
    float bv = xv1_b[c];
    #pragma unroll
    for (int ii=0;ii<4;ii++) acc[ii]=bv;
    for (int k = 0; k < 128; k += 4){
      float w0 = xv1_w[(k+0)*128+c], wq = xv1_w[(k+1)*128+c], wz = xv1_w[(k+2)*128+c], ww = xv1_w[(k+3)*128+c];
      #pragma unroll
      for (int ii=0;ii<4;ii++){
        float4 a = *(const float4*)&s_xn[ib+ii][k];
        acc[ii]=fmaf(a.x,w0,acc[ii]); acc[ii]=fmaf(a.y,wq,acc[ii]); acc[ii]=fmaf(a.z,wz,acc[ii]); acc[ii]=fmaf(a.w,ww,acc[ii]);
      }
    }
    for (int k = 0; k < 128; k += 4){
      float w0 = xv1_w[(128+k+0)*128+c], wq = xv1_w[(128+k+1)*128+c], wz = xv1_w[(128+k+2)*128+c], ww = xv1_w[(128+k+3)*128+c];
      #pragma unroll
      for (int ii=0;ii<4;ii++){
        float4 a = *(const float4*)&s_vn[ib+ii][k];
        acc[ii]=fmaf(a.x,w0,acc[ii]); acc[ii]=fmaf(a.y,wq,acc[ii]); acc[ii]=fmaf(a.z,wz,acc[ii]); acc[ii]=fmaf(a.w,ww,acc[ii]);
      }
    }
    #pragma unroll
    for (int ii=0;ii<4;ii++) s_h1[ib+ii][c] = ssilu_f(acc[ii]);
  }
  __syncthreads();
  // g = h1 @ xv2_w + b  (into s_v2)
  {
    int c = t & 127;
    int ib = (t >> 7) * 4;
    float a0[4], a1[4], a2[4];
    float bb0 = xv2_b[c], bb1 = xv2_b[c+128], bb2 = xv2_b[c+256];
    #pragma unroll
    for (int ii=0;ii<4;ii++){ a0[ii]=bb0; a1[ii]=bb1; a2[ii]=bb2; }
    for (int k = 0; k < 128; k += 4){
      float wa[4], wb[4], wc[4];
      #pragma unroll
      for (int j=0;j<4;j++){
        const float* wr = xv2_w + (size_t)(k+j)*384;
        wa[j]=wr[c]; wb[j]=wr[c+128]; wc[j]=wr[c+256];
      }
      #pragma unroll
      for (int ii=0;ii<4;ii++){
        float4 h4 = *(const float4*)&s_h1[ib+ii][k];
        a0[ii]=fmaf(h4.x,wa[0],a0[ii]); a0[ii]=fmaf(h4.y,wa[1],a0[ii]); a0[ii]=fmaf(h4.z,wa[2],a0[ii]); a0[ii]=fmaf(h4.w,wa[3],a0[ii]);
        a1[ii]=fmaf(h4.x,wb[0],a1[ii]); a1[ii]=fmaf(h4.y,wb[1],a1[ii]); a1[ii]=fmaf(h4.z,wb[2],a1[ii]); a1[ii]=fmaf(h4.w,wb[3],a1[ii]);
        a2[ii]=fmaf(h4.x,wc[0],a2[ii]); a2[ii]=fmaf(h4.y,wc[1],a2[ii]); a2[ii]=fmaf(h4.z,wc[2],a2[ii]); a2[ii]=fmaf(h4.w,wc[3],a2[ii]);
      }
    }
    #pragma unroll
    for (int ii=0;ii<4;ii++){
      int i = ib+ii;
      s_v2[i][c] = a0[ii]; s_v2[i][c+128] = a1[ii]; s_v2[i][c+256] = a2[ii];
    }
  }
  __syncthreads();
  #pragma unroll
  for (int rep = 0; rep < 4; rep++){
    int idx = rep*256 + t;
    int i = idx >> 7, h = idx & 127;
    float xout = s_xn[i][h] + (s_v2[i][h] + s_v2[i][128+h]*s_vd[i][h]) * INV_SQRT_2f;
    x[(size_t)(n0+i)*128 + h] = xout;
  }
  for (int idx = t; idx < 8*384; idx += 256){
    int i = idx / 384, r = idx % 384;
    int h = r & 127;
    vec[(size_t)(n0+i)*384 + r] = s_vl[i][r] + s_v2[i][256+h] * s_v1[i][r];
  }
}

// ---------------- final: energy + gated block 1 (8 nodes / block)
__global__ __launch_bounds__(256) void k_final1(
    const float* __restrict__ x, const float* __restrict__ vec,
    const float* __restrict__ we1, const float* __restrict__ be1,
    const float* __restrict__ we2, const float* __restrict__ be2,
    const float* __restrict__ wv1, const float* __restrict__ wv2,
    const float* __restrict__ wu1, const float* __restrict__ bu1,
    const float* __restrict__ wu2, const float* __restrict__ bu2,
    float* __restrict__ out, float* __restrict__ fx, float* __restrict__ fv)
{
  __shared__ __align__(16) float s_x[8][128];
  __shared__ __align__(16) float s_vl[8][384];
  __shared__ __align__(16) float s_p[8][384];
  __shared__ __align__(16) float s_n1[8][128];
  __shared__ __align__(16) float s_v2[8][192];
  __shared__ __align__(16) float s_h[8][128];
  __shared__ __align__(16) float s_h2[8][128];
  __shared__ __align__(16) float s_e1[8][64];
  int t = threadIdx.x;
  int n0 = blockIdx.x * 8;
  for (int idx = t; idx < 8*128; idx += 256){
    int i = idx >> 7, h = idx & 127;
    s_x[i][h] = x[(size_t)(n0+i)*128 + h];
  }
  for (int idx = t; idx < 8*384; idx += 256){
    int i = idx / 384, h = idx % 384;
    s_vl[i][h] = vec[(size_t)(n0+i)*384 + h];
  }
  __syncthreads();
  // energy hidden
  {
    int c = t & 63;
    int gb = t >> 6;
    #pragma unroll
    for (int u = 0; u < 2; u++){
      int i = gb + 4*u;
      float acc = be1[c];
      for (int k = 0; k < 128; k += 4){
        float w0 = we1[(k+0)*64+c], wq = we1[(k+1)*64+c], wz = we1[(k+2)*64+c], ww = we1[(k+3)*64+c];
        float4 a = *(const float4*)&s_x[i][k];
        acc = fmaf(a.x,w0,acc); acc=fmaf(a.y,wq,acc); acc=fmaf(a.z,wz,acc); acc=fmaf(a.w,ww,acc);
      }
      s_e1[i][c] = ssilu_f(acc);
    }
  }
  __syncthreads();
  {
    int lane = t & 63;
    int gb = t >> 6;
    #pragma unroll
    for (int u = 0; u < 2; u++){
      int i = gb + 4*u;
      float v = s_e1[i][lane] * we2[lane];
      #pragma unroll
      for (int off = 32; off > 0; off >>= 1) v += __shfl_xor(v, off, 64);
      if (lane == 0) out[(size_t)(n0+i)*4 + 0] = v + be2[0];
    }
  }
  // vp1 = vl @ wv1
  {
    int ob = t & 127;
    int ib = (t >> 7) * 4;
    float acc[4][3];
    #pragma unroll
    for (int ii=0;ii<4;ii++){
      #pragma unroll
      for (int cd=0;cd<3;cd++) acc[ii][cd]=0.f;
    }
    for (int k = 0; k < 128; k += 4){
      float w0 = wv1[(k+0)*128+ob], wq=wv1[(k+1)*128+ob], wz=wv1[(k+2)*128+ob], ww=wv1[(k+3)*128+ob];
      #pragma unroll
      for (int ii=0;ii<4;ii++){
        #pragma unroll
        for (int cd=0;cd<3;cd++){
          float4 a = *(const float4*)&s_vl[ib+ii][cd*128+k];
          float s0=acc[ii][cd];
          s0=fmaf(a.x,w0,s0); s0=fmaf(a.y,wq,s0); s0=fmaf(a.z,wz,s0); s0=fmaf(a.w,ww,s0);
          acc[ii][cd]=s0;
        }
      }
    }
    #pragma unroll
    for (int ii=0;ii<4;ii++){
      #pragma unroll
      for (int cd=0;cd<3;cd++) s_p[ib+ii][cd*128+ob] = acc[ii][cd];
    }
  }
  __syncthreads();
  #pragma unroll
  for (int rep = 0; rep < 4; rep++){
    int idx = rep*256+t;
    int i = idx >> 7, h = idx & 127;
    float p0 = s_p[i][h], p1 = s_p[i][128+h], p2 = s_p[i][256+h];
    s_n1[i][h] = sqrtf(p0*p0 + p1*p1 + p2*p2);
  }
  // vec2 = vl @ wv2
  {
    int c = t & 63;
    int gb = t >> 6;
    float acc[2][3];
    #pragma unroll
    for (int u=0;u<2;u++){
      #pragma unroll
      for (int cd=0;cd<3;cd++) acc[u][cd]=0.f;
    }
    for (int k=0;k<128;k+=4){
      float w0=wv2[(k+0)*64+c], wq=wv2[(k+1)*64+c], wz=wv2[(k+2)*64+c], ww=wv2[(k+3)*64+c];
      #pragma unroll
      for (int u=0;u<2;u++){
        int i = gb + 4*u;
        #pragma unroll
        for (int cd=0;cd<3;cd++){
          float4 a = *(const float4*)&s_vl[i][cd*128+k];
          float s0=acc[u][cd];
          s0=fmaf(a.x,w0,s0); s0=fmaf(a.y,wq,s0); s0=fmaf(a.z,wz,s0); s0=fmaf(a.w,ww,s0);
          acc[u][cd]=s0;
        }
      }
    }
    #pragma unroll
    for (int u=0;u<2;u++){
      int i=gb+4*u;
      #pragma unroll
      for (int cd=0;cd<3;cd++) s_v2[i][cd*64+c]=acc[u][cd];
    }
  }
  __syncthreads();
  // u1
  {
    int c = t & 127;
    int ib = (t >> 7) * 4;
    float acc[4];
    float bv = bu1[c];
    #pragma unroll
    for (int ii=0;ii<4;ii++) acc[ii]=bv;
    for (int k=0;k<128;k+=4){
      float w0=wu1[(k+0)*128+c], wq=wu1[(k+1)*128+c], wz=wu1[(k+2)*128+c], ww=wu1[(k+3)*128+c];
      #pragma unroll
      for (int ii=0;ii<4;ii++){
        float4 a = *(const float4*)&s_x[ib+ii][k];
        acc[ii]=fmaf(a.x,w0,acc[ii]); acc[ii]=fmaf(a.y,wq,acc[ii]); acc[ii]=fmaf(a.z,wz,acc[ii]); acc[ii]=fmaf(a.w,ww,acc[ii]);
      }
    }
    for (int k=0;k<128;k+=4){
      float w0=wu1[(128+k+0)*128+c], wq=wu1[(128+k+1)*128+c], wz=wu1[(128+k+2)*128+c], ww=wu1[(128+k+3)*128+c];
      #pragma unroll
      for (int ii=0;ii<4;ii++){
        float4 a = *(const float4*)&s_n1[ib+ii][k];
        acc[ii]=fmaf(a.x,w0,acc[ii]); acc[ii]=fmaf(a.y,wq,acc[ii]); acc[ii]=fmaf(a.z,wz,acc[ii]); acc[ii]=fmaf(a.w,ww,acc[ii]);
      }
    }
    #pragma unroll
    for (int ii=0;ii<4;ii++) s_h[ib+ii][c] = ssilu_f(acc[ii]);
  }
  __syncthreads();
  // u2
  {
    int c = t & 127;
    int ib = (t >> 7) * 4;
    float acc[4];
    float bv = bu2[c];
    #pragma unroll
    for (int ii=0;ii<4;ii++) acc[ii]=bv;
    for (int k=0;k<128;k+=4){
      float w0=wu2[(k+0)*128+c], wq=wu2[(k+1)*128+c], wz=wu2[(k+2)*128+c], ww=wu2[(k+3)*128+c];
      #pragma unroll
      for (int ii=0;ii<4;ii++){
        float4 a = *(const float4*)&s_h[ib+ii][k];
        acc[ii]=fmaf(a.x,w0,acc[ii]); acc[ii]=fmaf(a.y,wq,acc[ii]); acc[ii]=fmaf(a.z,wz,acc[ii]); acc[ii]=fmaf(a.w,ww,acc[ii]);
      }
    }
    #pragma unroll
    for (int ii=0;ii<4;ii++) s_h2[ib+ii][c] = acc[ii];
  }
  __syncthreads();
  {
    int c = t & 63;
    int gb = t >> 6;
    #pragma unroll
    for (int u=0;u<2;u++){
      int i = gb + 4*u;
      fx[(size_t)(n0+i)*64 + c] = ssilu_f(s_h2[i][c]);
      float xv = s_h2[i][64+c];
      #pragma unroll
      for (int cd=0;cd<3;cd++)
        fv[(size_t)(n0+i)*192 + cd*64 + c] = xv * s_v2[i][cd*64+c];
    }
  }
}

// ---------------- final: gated block 2 -> forces (1 node / wave)
__global__ __launch_bounds__(256) void k_final2(
    const float* __restrict__ fx, const float* __restrict__ fv,
    const float* __restrict__ wv1, const float* __restrict__ wv2,
    const float* __restrict__ wu1, const float* __restrict__ bu1,
    const float* __restrict__ wu2, const float* __restrict__ bu2,
    float* __restrict__ out)
{
  int t = threadIdx.x;
  int lane = t & 63;
  int n = blockIdx.x * 4 + (t >> 6);
  float fxv = fx[(size_t)n*64 + lane];
  float f0 = fv[(size_t)n*192 + lane];
  float f1 = fv[(size_t)n*192 + 64 + lane];
  float f2 = fv[(size_t)n*192 + 128 + lane];
  float a0=0.f, a1=0.f, a2=0.f;
  for (int k=0;k<64;k++){
    float w = wv1[k*64 + lane];
    a0 = fmaf(bcast(f0,k), w, a0);
    a1 = fmaf(bcast(f1,k), w, a1);
    a2 = fmaf(bcast(f2,k), w, a2);
  }
  float n1 = sqrtf(a0*a0 + a1*a1 + a2*a2);
  float w2v = wv2[lane];
  float r0 = f0*w2v, r1 = f1*w2v, r2 = f2*w2v;
  #pragma unroll
  for (int off=32; off>0; off>>=1){
    r0 += __shfl_xor(r0, off, 64);
    r1 += __shfl_xor(r1, off, 64);
    r2 += __shfl_xor(r2, off, 64);
  }
  float acc = bu1[lane];
  for (int k=0;k<64;k++) acc = fmaf(bcast(fxv,k), wu1[k*64+lane], acc);
  for (int k=0;k<64;k++) acc = fmaf(bcast(n1,k), wu1[(64+k)*64+lane], acc);
  float hv = ssilu_f(acc);
  float s1 = hv * wu2[lane*2 + 1];
  #pragma unroll
  for (int off=32; off>0; off>>=1) s1 += __shfl_xor(s1, off, 64);
  float h2_1 = s1 + bu2[1];
  if (lane == 0){
    out[(size_t)n*4 + 1] = h2_1 * r0;
    out[(size_t)n*4 + 2] = h2_1 * r1;
    out[(size_t)n*4 + 3] = h2_1 * r2;
  }
}

extern "C" void kernel_launch(void* const* d_in, const int* in_sizes, int n_in,
                              void* d_out, int out_size, void* d_ws, size_t ws_size,
                              hipStream_t stream)
{
  const float* x_in   = (const float*)d_in[0];
  const float* vec_in = (const float*)d_in[1];
  const int*   eidx   = (const int*)d_in[2];
  const float* erbf   = (const float*)d_in[3];
  const float* evec   = (const float*)d_in[4];
  const float* ln_w  = (const float*)d_in[5];
  const float* ln_b  = (const float*)d_in[6];
  const float* xp1_w = (const float*)d_in[7];
  const float* xp1_b = (const float*)d_in[8];
  const float* xp2_w = (const float*)d_in[9];
  const float* xp2_b = (const float*)d_in[10];
  const float* rbf_w = (const float*)d_in[11];
  const float* rbf_b = (const float*)d_in[12];
  const float* vp_w  = (const float*)d_in[13];
  const float* xv1_w = (const float*)d_in[14];
  const float* xv1_b = (const float*)d_in[15];
  const float* xv2_w = (const float*)d_in[16];
  const float* xv2_b = (const float*)d_in[17];
  const float* we1 = (const float*)d_in[18];
  const float* be1 = (const float*)d_in[19];
  const float* we2 = (const float*)d_in[20];
  const float* be2 = (const float*)d_in[21];
  const float* g1_v1 = (const float*)d_in[22];
  const float* g1_v2 = (const float*)d_in[23];
  const float* g1_u1 = (const float*)d_in[24];
  const float* g1_u1b = (const float*)d_in[25];
  const float* g1_u2 = (const float*)d_in[26];
  const float* g1_u2b = (const float*)d_in[27];
  const float* g2_v1 = (const float*)d_in[28];
  const float* g2_v2 = (const float*)d_in[29];
  const float* g2_u1 = (const float*)d_in[30];
  const float* g2_u1b = (const float*)d_in[31];
  const float* g2_u2 = (const float*)d_in[32];
  const float* g2_u2b = (const float*)d_in[33];
  float* out = (float*)d_out;

  float* ws = (float*)d_ws;
  float* x_cur   = ws;                       // N*128
  float* vec_cur = x_cur + (size_t)NN*128;   // N*384
  float* dx      = vec_cur + (size_t)NN*384; // N*128
  float* dvec    = dx + (size_t)NN*128;      // N*384 (contiguous with dx)
  float* xh      = dvec + (size_t)NN*384;    // N*384
  float* fxb     = xh;                       // N*64 (reuse)
  float* fvb     = xh + (size_t)NN*64;       // N*192

  hipMemcpyAsync(x_cur, x_in, sizeof(float)*(size_t)NN*128, hipMemcpyDeviceToDevice, stream);
  hipMemcpyAsync(vec_cur, vec_in, sizeof(float)*(size_t)NN*384, hipMemcpyDeviceToDevice, stream);

  const int* esrc = eidx;
  const int* edst = eidx + EE;

  for (int l = 0; l < LL; l++){
    hipMemsetAsync(dx, 0, sizeof(float)*(size_t)NN*512, stream);
    k_xh<<<NN/16, 256, 0, stream>>>(x_cur, ln_w + l*128, ln_b + l*128,
        xp1_w + (size_t)l*128*128, xp1_b + l*128,
        xp2_w + (size_t)l*128*384, xp2_b + l*384, xh);
    k_edge<<<768, 512, 0, stream>>>(erbf, rbf_w + (size_t)l*64*384, rbf_b + l*384,
        esrc, edst, evec, xh, vec_cur, dx, dvec);
    k_node<<<NN/8, 256, 0, stream>>>(vp_w + (size_t)l*128*256,
        xv1_w + (size_t)l*256*128, xv1_b + l*128,
        xv2_w + (size_t)l*128*384, xv2_b + l*384,
        dx, dvec, x_cur, vec_cur);
  }
  k_final1<<<NN/8, 256, 0, stream>>>(x_cur, vec_cur, we1, be1, we2, be2,
      g1_v1, g1_v2, g1_u1, g1_u1b, g1_u2, g1_u2b, out, fxb, fvb);
  k_final2<<<NN/4, 256, 0, stream>>>(fxb, fvb, g2_v1, g2_v2, g2_u1, g2_u1b, g2_u2, g2_u2b, out);
}

// Round 2
// 2237.808 us; speedup vs baseline: 1.2137x; 1.2137x over previous
//
#include <hip/hip_runtime.h>
#include <hip/hip_bf16.h>

#define NN 10000
#define EE 160000
#define LL 6

#define INV_SQRT_3f  0.57735026919f
#define INV_SQRT_Hf  0.08838834764832f
#define INV_SQRT_2f  0.70710678118655f

__device__ __forceinline__ float ssilu_f(float v){
  float s = 1.0f / (1.0f + __expf(-v));
  return v * s * 1.6666666666667f;
}
__device__ __forceinline__ float bcast(float v, int l){
  return __int_as_float(__builtin_amdgcn_readlane(__float_as_int(v), l));
}
__device__ __forceinline__ float uif(unsigned u){ return __uint_as_float(u); }

// ---------------- CSR build ----------------
__global__ __launch_bounds__(256) void k_hist(const int* __restrict__ edst, int* __restrict__ cnt){
  int i = blockIdx.x*256 + threadIdx.x;
  if (i < EE) atomicAdd(&cnt[edst[i]], 1);
}

__global__ __launch_bounds__(1024) void k_scan(const int* __restrict__ cnt,
                                               int* __restrict__ off, int* __restrict__ cur){
  __shared__ int ps[1024];
  int t = threadIdx.x;
  int base = t*10;
  int local[10];
  int s = 0;
  #pragma unroll
  for (int i=0;i<10;i++){
    int c = (base+i < NN) ? cnt[base+i] : 0;
    local[i] = s; s += c;
  }
  ps[t] = s;
  __syncthreads();
  for (int d=1; d<1024; d<<=1){
    int v = (t>=d) ? ps[t-d] : 0;
    __syncthreads();
    ps[t] += v;
    __syncthreads();
  }
  int pre = (t>0) ? ps[t-1] : 0;
  #pragma unroll
  for (int i=0;i<10;i++){
    int idx = base+i;
    if (idx < NN){ int o = pre + local[i]; off[idx]=o; cur[idx]=o; }
  }
  if (t==1023) off[NN] = ps[1023];
}

__global__ __launch_bounds__(256) void k_fill(const int* __restrict__ edst,
                                              int* __restrict__ cur, int* __restrict__ eord){
  int i = blockIdx.x*256 + threadIdx.x;
  if (i < EE){
    int d = edst[i];
    int p = atomicAdd(&cur[d], 1);
    eord[p] = i;
  }
}

// ---------------- pack rbf_w (all layers) to bf16x2, layout [l][r][jp*64+lane] ----------------
__global__ __launch_bounds__(256) void k_cvtw(const float* __restrict__ w, unsigned* __restrict__ wpk){
  int i = blockIdx.x*256 + threadIdx.x;           // 6*64*192
  if (i >= LL*64*192) return;
  int l    = i / (64*192);
  int rr   = (i / 192) % 64;
  int rem  = i % 192;
  int jp   = rem >> 6;
  int lane = rem & 63;
  const float* base = w + (size_t)l*64*384 + (size_t)rr*384;
  float lo = base[jp*128 + lane];
  float hi = base[jp*128 + 64 + lane];
  union { __hip_bfloat16 h; unsigned short u; } ca, cb;
  ca.h = __float2bfloat16(lo); cb.h = __float2bfloat16(hi);
  wpk[i] = (unsigned)ca.u | ((unsigned)cb.u << 16);
}

// ---------------- xh = ssilu(lnorm(x)@xp1+b)@xp2+b   (16 nodes / 256-thr block)
__global__ __launch_bounds__(256) void k_xh(
    const float* __restrict__ x,
    const float* __restrict__ lnw, const float* __restrict__ lnb,
    const float* __restrict__ w1, const float* __restrict__ b1,
    const float* __restrict__ w2, const float* __restrict__ b2,
    float* __restrict__ xh)
{
  __shared__ __align__(16) float s_xn[16][128];
  __shared__ __align__(16) float s_h1[16][128];
  int t = threadIdx.x;
  int n0 = blockIdx.x * 16;
  {
    int r = t >> 4, cc = t & 15;
    const float* xr = x + (size_t)(n0 + r) * 128;
    float v[8];
    float s = 0.f, ss = 0.f;
    #pragma unroll
    for (int u = 0; u < 8; u++){
      v[u] = xr[cc + 16*u];
      s += v[u]; ss += v[u]*v[u];
    }
    #pragma unroll
    for (int off = 8; off > 0; off >>= 1){
      s  += __shfl_xor(s, off, 16);
      ss += __shfl_xor(ss, off, 16);
    }
    float mean = s * (1.0f/128.0f);
    float var  = ss * (1.0f/128.0f) - mean*mean;
    float rstd = rsqrtf(var + 1e-5f);
    #pragma unroll
    for (int u = 0; u < 8; u++){
      int h = cc + 16*u;
      s_xn[r][h] = (v[u] - mean) * rstd * lnw[h] + lnb[h];
    }
  }
  __syncthreads();
  {
    int c = t & 127;
    int rb = t >> 7;
    float acc[8];
    float bv = b1[c];
    #pragma unroll
    for (int u = 0; u < 8; u++) acc[u] = bv;
    for (int k = 0; k < 128; k += 4){
      float w0 = w1[(k+0)*128 + c];
      float wq = w1[(k+1)*128 + c];
      float wz = w1[(k+2)*128 + c];
      float ww = w1[(k+3)*128 + c];
      #pragma unroll
      for (int u = 0; u < 8; u++){
        float4 xv = *(const float4*)&s_xn[rb + 2*u][k];
        acc[u] = fmaf(xv.x, w0, acc[u]);
        acc[u] = fmaf(xv.y, wq, acc[u]);
        acc[u] = fmaf(xv.z, wz, acc[u]);
        acc[u] = fmaf(xv.w, ww, acc[u]);
      }
    }
    #pragma unroll
    for (int u = 0; u < 8; u++) s_h1[rb + 2*u][c] = ssilu_f(acc[u]);
  }
  __syncthreads();
  {
    int c = t & 127;
    int rb = t >> 7;
    float a0[8], a1[8], a2[8];
    float bb0 = b2[c], bb1 = b2[c+128], bb2 = b2[c+256];
    #pragma unroll
    for (int u=0;u<8;u++){ a0[u]=bb0; a1[u]=bb1; a2[u]=bb2; }
    for (int k = 0; k < 128; k += 4){
      float wa[4], wb[4], wc[4];
      #pragma unroll
      for (int j=0;j<4;j++){
        const float* wr = w2 + (size_t)(k+j)*384;
        wa[j]=wr[c]; wb[j]=wr[c+128]; wc[j]=wr[c+256];
      }
      #pragma unroll
      for (int u = 0; u < 8; u++){
        float4 hv = *(const float4*)&s_h1[rb + 2*u][k];
        a0[u]=fmaf(hv.x,wa[0],a0[u]); a0[u]=fmaf(hv.y,wa[1],a0[u]); a0[u]=fmaf(hv.z,wa[2],a0[u]); a0[u]=fmaf(hv.w,wa[3],a0[u]);
        a1[u]=fmaf(hv.x,wb[0],a1[u]); a1[u]=fmaf(hv.y,wb[1],a1[u]); a1[u]=fmaf(hv.z,wb[2],a1[u]); a1[u]=fmaf(hv.w,wb[3],a1[u]);
        a2[u]=fmaf(hv.x,wc[0],a2[u]); a2[u]=fmaf(hv.y,wc[1],a2[u]); a2[u]=fmaf(hv.z,wc[2],a2[u]); a2[u]=fmaf(hv.w,wc[3],a2[u]);
      }
    }
    #pragma unroll
    for (int u = 0; u < 8; u++){
      float* o = xh + (size_t)(n0 + rb + 2*u) * 384;
      o[c] = a0[u]; o[c+128] = a1[u]; o[c+256] = a2[u];
    }
  }
}

// ---------------- edge kernel, dst-side, no atomics: one wave per dst node
__global__ __launch_bounds__(256) void k_edge2(
    const unsigned* __restrict__ wpk,     // [64][192] packed bf16x2, this layer
    const float* __restrict__ rbf_b,
    const float* __restrict__ erbf,
    const int* __restrict__ esrc,
    const int* __restrict__ eord, const int* __restrict__ off,
    const float* __restrict__ evec,
    const float* __restrict__ xh, const float* __restrict__ vec,
    float* __restrict__ dx, float* __restrict__ dvec)
{
  __shared__ unsigned wl[64*192];
  int t = threadIdx.x;
  {
    const uint4* src4 = (const uint4*)wpk;
    uint4* dst4 = (uint4*)wl;
    #pragma unroll
    for (int i = t; i < 64*192/4; i += 256) dst4[i] = src4[i];
  }
  __syncthreads();
  int lane = t & 63;
  int wv = blockIdx.x*4 + (t>>6);
  int nwaves = gridDim.x*4;
  float bias[6];
  #pragma unroll
  for (int j=0;j<6;j++) bias[j] = rbf_b[j*64 + lane];
  for (int n = wv; n < NN; n += nwaves){
    int o0 = off[n], o1 = off[n+1];
    float ax0 = 0.f, ax1 = 0.f;
    float av00=0.f, av01=0.f, av10=0.f, av11=0.f, av20=0.f, av21=0.f;
    for (int p = o0; p < o1; p += 4){
      int ne = o1 - p; if (ne > 4) ne = 4;
      int e[4]; float rv[4];
      #pragma unroll
      for (int q=0;q<4;q++){
        int idx = (q < ne) ? (p+q) : p;
        e[q] = eord[idx];
      }
      #pragma unroll
      for (int q=0;q<4;q++) rv[q] = erbf[(size_t)e[q]*64 + lane];
      float acc[4][6];
      #pragma unroll
      for (int q=0;q<4;q++){
        #pragma unroll
        for (int j=0;j<6;j++) acc[q][j] = bias[j];
      }
      #pragma unroll 2
      for (int r = 0; r < 64; r++){
        unsigned u0 = wl[r*192 +       lane];
        unsigned u1 = wl[r*192 +  64 + lane];
        unsigned u2 = wl[r*192 + 128 + lane];
        float w0 = uif(u0 << 16), w1 = uif(u0 & 0xffff0000u);
        float w2 = uif(u1 << 16), w3 = uif(u1 & 0xffff0000u);
        float w4 = uif(u2 << 16), w5 = uif(u2 & 0xffff0000u);
        #pragma unroll
        for (int q=0;q<4;q++){
          float bv = bcast(rv[q], r);
          acc[q][0] = fmaf(bv, w0, acc[q][0]);
          acc[q][1] = fmaf(bv, w1, acc[q][1]);
          acc[q][2] = fmaf(bv, w2, acc[q][2]);
          acc[q][3] = fmaf(bv, w3, acc[q][3]);
          acc[q][4] = fmaf(bv, w4, acc[q][4]);
          acc[q][5] = fmaf(bv, w5, acc[q][5]);
        }
      }
      #pragma unroll
      for (int q=0;q<4;q++){
        if (q < ne){
          int eid = e[q];
          int sN = esrc[eid];
          const float* xr = xh + (size_t)sN * 384;
          float m0  = acc[q][0] * xr[lane];
          float m1  = acc[q][1] * xr[64+lane];
          float m2a = acc[q][2] * xr[128+lane] * INV_SQRT_3f;
          float m2b = acc[q][3] * xr[192+lane] * INV_SQRT_3f;
          float m3a = acc[q][4] * xr[256+lane];
          float m3b = acc[q][5] * xr[320+lane];
          ax0 += m0; ax1 += m1;
          const float* vr = vec + (size_t)sN * 384;
          float ev0 = evec[(size_t)eid*3 + 0];
          float ev1 = evec[(size_t)eid*3 + 1];
          float ev2 = evec[(size_t)eid*3 + 2];
          av00 = fmaf(vr[lane],        m2a, av00); av00 = fmaf(m3a, ev0, av00);
          av01 = fmaf(vr[64+lane],     m2b, av01); av01 = fmaf(m3b, ev0, av01);
          av10 = fmaf(vr[128+lane],    m2a, av10); av10 = fmaf(m3a, ev1, av10);
          av11 = fmaf(vr[192+lane],    m2b, av11); av11 = fmaf(m3b, ev1, av11);
          av20 = fmaf(vr[256+lane],    m2a, av20); av20 = fmaf(m3a, ev2, av20);
          av21 = fmaf(vr[320+lane],    m2b, av21); av21 = fmaf(m3b, ev2, av21);
        }
      }
    }
    float* dxr = dx + (size_t)n*128;
    dxr[lane] = ax0; dxr[64+lane] = ax1;
    float* dvr = dvec + (size_t)n*384;
    dvr[lane]       = av00 * INV_SQRT_Hf;
    dvr[64+lane]    = av01 * INV_SQRT_Hf;
    dvr[128+lane]   = av10 * INV_SQRT_Hf;
    dvr[192+lane]   = av11 * INV_SQRT_Hf;
    dvr[256+lane]   = av20 * INV_SQRT_Hf;
    dvr[320+lane]   = av21 * INV_SQRT_Hf;
  }
}

// ---------------- node update: x,vec += agg; vp; vec_dot/vnorm; xv MLP; final (8 nodes/block)
__global__ __launch_bounds__(256) void k_node(
    const float* __restrict__ vp_w,
    const float* __restrict__ xv1_w, const float* __restrict__ xv1_b,
    const float* __restrict__ xv2_w, const float* __restrict__ xv2_b,
    const float* __restrict__ dx, const float* __restrict__ dvec,
    float* __restrict__ x, float* __restrict__ vec)
{
  __shared__ __align__(16) float s_xn[8][128];
  __shared__ __align__(16) float s_vl[8][384];
  __shared__ __align__(16) float s_v1[8][384];
  __shared__ __align__(16) float s_v2[8][384];
  __shared__ __align__(16) float s_vd[8][128];
  __shared__ __align__(16) float s_vn[8][128];
  __shared__ __align__(16) float s_h1[8][128];
  int t = threadIdx.x;
  int n0 = blockIdx.x * 8;
  for (int idx = t; idx < 8*128; idx += 256){
    int i = idx >> 7, h = idx & 127;
    size_t p = (size_t)(n0+i)*128 + h;
    s_xn[i][h] = (x[p] + dx[p]) * INV_SQRT_2f;
  }
  for (int idx = t; idx < 8*384; idx += 256){
    int i = idx / 384, h = idx % 384;
    size_t p = (size_t)(n0+i)*384 + h;
    s_vl[i][h] = vec[p] + dvec[p];
  }
  __syncthreads();
  {
    int ob = t & 127;
    int ib = (t >> 7) * 4;
    float acc0[4][3], acc1[4][3];
    #pragma unroll
    for (int ii=0;ii<4;ii++){
      #pragma unroll
      for (int cd=0;cd<3;cd++){ acc0[ii][cd]=0.f; acc1[ii][cd]=0.f; }
    }
    for (int k = 0; k < 128; k += 4){
      float wA[4], wB[4];
      #pragma unroll
      for (int j=0;j<4;j++){
        const float* wr = vp_w + (size_t)(k+j)*256;
        wA[j] = wr[ob]; wB[j] = wr[ob+128];
      }
      #pragma unroll
      for (int ii = 0; ii < 4; ii++){
        #pragma unroll
        for (int cd = 0; cd < 3; cd++){
          float4 a = *(const float4*)&s_vl[ib+ii][cd*128 + k];
          float s0 = acc0[ii][cd], s1 = acc1[ii][cd];
          s0 = fmaf(a.x, wA[0], s0); s0 = fmaf(a.y, wA[1], s0); s0 = fmaf(a.z, wA[2], s0); s0 = fmaf(a.w, wA[3], s0);
          s1 = fmaf(a.x, wB[0], s1); s1 = fmaf(a.y, wB[1], s1); s1 = fmaf(a.z, wB[2], s1); s1 = fmaf(a.w, wB[3], s1);
          acc0[ii][cd] = s0; acc1[ii][cd] = s1;
        }
      }
    }
    #pragma unroll
    for (int ii = 0; ii < 4; ii++){
      #pragma unroll
      for (int cd = 0; cd < 3; cd++){
        s_v1[ib+ii][cd*128 + ob] = acc0[ii][cd];
        s_v2[ib+ii][cd*128 + ob] = acc1[ii][cd];
      }
    }
  }
  __syncthreads();
  #pragma unroll
  for (int rep = 0; rep < 4; rep++){
    int idx = rep*256 + t;
    int i = idx >> 7, h = idx & 127;
    float a0 = s_v1[i][h],     b0 = s_v2[i][h];
    float a1 = s_v1[i][128+h], b1 = s_v2[i][128+h];
    float a2 = s_v1[i][256+h], b2 = s_v2[i][256+h];
    s_vd[i][h] = (a0*b0 + a1*b1 + a2*b2) * INV_SQRT_Hf;
    s_vn[i][h] = sqrtf(b0*b0 + b1*b1 + b2*b2 + 1e-8f);
  }
  __syncthreads();
  {
    int c = t & 127;
    int ib = (t >> 7) * 4;
    float acc[4];
    float bv = xv1_b[c];
    #pragma unroll
    for (int ii=0;ii<4;ii++) acc[ii]=bv;
    for (int k = 0; k < 128; k += 4){
      float w0 = xv1_w[(k+0)*128+c], wq = xv1_w[(k+1)*128+c], wz = xv1_w[(k+2)*128+c], ww = xv1_w[(k+3)*128+c];
      #pragma unroll
      for (int ii=0;ii<4;ii++){
        float4 a = *(const float4*)&s_xn[ib+ii][k];
        acc[ii]=fmaf(a.x,w0,acc[ii]); acc[ii]=fmaf(a.y,wq,acc[ii]); acc[ii]=fmaf(a.z,wz,acc[ii]); acc[ii]=fmaf(a.w,ww,acc[ii]);
      }
    }
    for (int k = 0; k < 128; k += 4){
      float w0 = xv1_w[(128+k+0)*128+c], wq = xv1_w[(128+k+1)*128+c], wz = xv1_w[(128+k+2)*128+c], ww = xv1_w[(128+k+3)*128+c];
      #pragma unroll
      for (int ii=0;ii<4;ii++){
        float4 a = *(const float4*)&s_vn[ib+ii][k];
        acc[ii]=fmaf(a.x,w0,acc[ii]); acc[ii]=fmaf(a.y,wq,acc[ii]); acc[ii]=fmaf(a.z,wz,acc[ii]); acc[ii]=fmaf(a.w,ww,acc[ii]);
      }
    }
    #pragma unroll
    for (int ii=0;ii<4;ii++) s_h1[ib+ii][c] = ssilu_f(acc[ii]);
  }
  __syncthreads();
  {
    int c = t & 127;
    int ib = (t >> 7) * 4;
    float a0[4], a1[4], a2[4];
    float bb0 = xv2_b[c], bb1 = xv2_b[c+128], bb2 = xv2_b[c+256];
    #pragma unroll
    for (int ii=0;ii<4;ii++){ a0[ii]=bb0; a1[ii]=bb1; a2[ii]=bb2; }
    for (int k = 0; k < 128; k += 4){
      float wa[4], wb[4], wc[4];
      #pragma unroll
      for (int j=0;j<4;j++){
        const float* wr = xv2_w + (size_t)(k+j)*384;
        wa[j]=wr[c]; wb[j]=wr[c+128]; wc[j]=wr[c+256];
      }
      #pragma unroll
      for (int ii=0;ii<4;ii++){
        float4 h4 = *(const float4*)&s_h1[ib+ii][k];
        a0[ii]=fmaf(h4.x,wa[0],a0[ii]); a0[ii]=fmaf(h4.y,wa[1],a0[ii]); a0[ii]=fmaf(h4.z,wa[2],a0[ii]); a0[ii]=fmaf(h4.w,wa[3],a0[ii]);
        a1[ii]=fmaf(h4.x,wb[0],a1[ii]); a1[ii]=fmaf(h4.y,wb[1],a1[ii]); a1[ii]=fmaf(h4.z,wb[2],a1[ii]); a1[ii]=fmaf(h4.w,wb[3],a1[ii]);
        a2[ii]=fmaf(h4.x,wc[0],a2[ii]); a2[ii]=fmaf(h4.y,wc[1],a2[ii]); a2[ii]=fmaf(h4.z,wc[2],a2[ii]); a2[ii]=fmaf(h4.w,wc[3],a2[ii]);
      }
    }
    #pragma unroll
    for (int ii=0;ii<4;ii++){
      int i = ib+ii;
      s_v2[i][c] = a0[ii]; s_v2[i][c+128] = a1[ii]; s_v2[i][c+256] = a2[ii];
    }
  }
  __syncthreads();
  #pragma unroll
  for (int rep = 0; rep < 4; rep++){
    int idx = rep*256 + t;
    int i = idx >> 7, h = idx & 127;
    float xout = s_xn[i][h] + (s_v2[i][h] + s_v2[i][128+h]*s_vd[i][h]) * INV_SQRT_2f;
    x[(size_t)(n0+i)*128 + h] = xout;
  }
  for (int idx = t; idx < 8*384; idx += 256){
    int i = idx / 384, r = idx % 384;
    int h = r & 127;
    vec[(size_t)(n0+i)*384 + r] = s_vl[i][r] + s_v2[i][256+h] * s_v1[i][r];
  }
}

// ---------------- final: energy + gated block 1 (8 nodes / block)
__global__ __launch_bounds__(256) void k_final1(
    const float* __restrict__ x, const float* __restrict__ vec,
    const float* __restrict__ we1, const float* __restrict__ be1,
    const float* __restrict__ we2, const float* __restrict__ be2,
    const float* __restrict__ wv1, const float* __restrict__ wv2,
    const float* __restrict__ wu1, const float* __restrict__ bu1,
    const float* __restrict__ wu2, const float* __restrict__ bu2,
    float* __restrict__ out, float* __restrict__ fx, float* __restrict__ fv)
{
  __shared__ __align__(16) float s_x[8][128];
  __shared__ __align__(16) float s_vl[8][384];
  __shared__ __align__(16) float s_p[8][384];
  __shared__ __align__(16) float s_n1[8][128];
  __shared__ __align__(16) float s_v2[8][192];
  __shared__ __align__(16) float s_h[8][128];
  __shared__ __align__(16) float s_h2[8][128];
  __shared__ __align__(16) float s_e1[8][64];
  int t = threadIdx.x;
  int n0 = blockIdx.x * 8;
  for (int idx = t; idx < 8*128; idx += 256){
    int i = idx >> 7, h = idx & 127;
    s_x[i][h] = x[(size_t)(n0+i)*128 + h];
  }
  for (int idx = t; idx < 8*384; idx += 256){
    int i = idx / 384, h = idx % 384;
    s_vl[i][h] = vec[(size_t)(n0+i)*384 + h];
  }
  __syncthreads();
  {
    int c = t & 63;
    int gb = t >> 6;
    #pragma unroll
    for (int u = 0; u < 2; u++){
      int i = gb + 4*u;
      float acc = be1[c];
      for (int k = 0; k < 128; k += 4){
        float w0 = we1[(k+0)*64+c], wq = we1[(k+1)*64+c], wz = we1[(k+2)*64+c], ww = we1[(k+3)*64+c];
        float4 a = *(const float4*)&s_x[i][k];
        acc = fmaf(a.x,w0,acc); acc=fmaf(a.y,wq,acc); acc=fmaf(a.z,wz,acc); acc=fmaf(a.w,ww,acc);
      }
      s_e1[i][c] = ssilu_f(acc);
    }
  }
  __syncthreads();
  {
    int lane = t & 63;
    int gb = t >> 6;
    #pragma unroll
    for (int u = 0; u < 2; u++){
      int i = gb + 4*u;
      float v = s_e1[i][lane] * we2[lane];
      #pragma unroll
      for (int off = 32; off > 0; off >>= 1) v += __shfl_xor(v, off, 64);
      if (lane == 0) out[(size_t)(n0+i)*4 + 0] = v + be2[0];
    }
  }
  {
    int ob = t & 127;
    int ib = (t >> 7) * 4;
    float acc[4][3];
    #pragma unroll
    for (int ii=0;ii<4;ii++){
      #pragma unroll
      for (int cd=0;cd<3;cd++) acc[ii][cd]=0.f;
    }
    for (int k = 0; k < 128; k += 4){
      float w0 = wv1[(k+0)*128+ob], wq=wv1[(k+1)*128+ob], wz=wv1[(k+2)*128+ob], ww=wv1[(k+3)*128+ob];
      #pragma unroll
      for (int ii=0;ii<4;ii++){
        #pragma unroll
        for (int cd=0;cd<3;cd++){
          float4 a = *(const float4*)&s_vl[ib+ii][cd*128+k];
          float s0=acc[ii][cd];
          s0=fmaf(a.x,w0,s0); s0=fmaf(a.y,wq,s0); s0=fmaf(a.z,wz,s0); s0=fmaf(a.w,ww,s0);
          acc[ii][cd]=s0;
        }
      }
    }
    #pragma unroll
    for (int ii=0;ii<4;ii++){
      #pragma unroll
      for (int cd=0;cd<3;cd++) s_p[ib+ii][cd*128+ob] = acc[ii][cd];
    }
  }
  __syncthreads();
  #pragma unroll
  for (int rep = 0; rep < 4; rep++){
    int idx = rep*256+t;
    int i = idx >> 7, h = idx & 127;
    float p0 = s_p[i][h], p1 = s_p[i][128+h], p2 = s_p[i][256+h];
    s_n1[i][h] = sqrtf(p0*p0 + p1*p1 + p2*p2);
  }
  {
    int c = t & 63;
    int gb = t >> 6;
    float acc[2][3];
    #pragma unroll
    for (int u=0;u<2;u++){
      #pragma unroll
      for (int cd=0;cd<3;cd++) acc[u][cd]=0.f;
    }
    for (int k=0;k<128;k+=4){
      float w0=wv2[(k+0)*64+c], wq=wv2[(k+1)*64+c], wz=wv2[(k+2)*64+c], ww=wv2[(k+3)*64+c];
      #pragma unroll
      for (int u=0;u<2;u++){
        int i = gb + 4*u;
        #pragma unroll
        for (int cd=0;cd<3;cd++){
          float4 a = *(const float4*)&s_vl[i][cd*128+k];
          float s0=acc[u][cd];
          s0=fmaf(a.x,w0,s0); s0=fmaf(a.y,wq,s0); s0=fmaf(a.z,wz,s0); s0=fmaf(a.w,ww,s0);
          acc[u][cd]=s0;
        }
      }
    }
    #pragma unroll
    for (int u=0;u<2;u++){
      int i=gb+4*u;
      #pragma unroll
      for (int cd=0;cd<3;cd++) s_v2[i][cd*64+c]=acc[u][cd];
    }
  }
  __syncthreads();
  {
    int c = t & 127;
    int ib = (t >> 7) * 4;
    float acc[4];
    float bv = bu1[c];
    #pragma unroll
    for (int ii=0;ii<4;ii++) acc[ii]=bv;
    for (int k=0;k<128;k+=4){
      float w0=wu1[(k+0)*128+c], wq=wu1[(k+1)*128+c], wz=wu1[(k+2)*128+c], ww=wu1[(k+3)*128+c];
      #pragma unroll
      for (int ii=0;ii<4;ii++){
        float4 a = *(const float4*)&s_x[ib+ii][k];
        acc[ii]=fmaf(a.x,w0,acc[ii]); acc[ii]=fmaf(a.y,wq,acc[ii]); acc[ii]=fmaf(a.z,wz,acc[ii]); acc[ii]=fmaf(a.w,ww,acc[ii]);
      }
    }
    for (int k=0;k<128;k+=4){
      float w0=wu1[(128+k+0)*128+c], wq=wu1[(128+k+1)*128+c], wz=wu1[(128+k+2)*128+c], ww=wu1[(128+k+3)*128+c];
      #pragma unroll
      for (int ii=0;ii<4;ii++){
        float4 a = *(const float4*)&s_n1[ib+ii][k];
        acc[ii]=fmaf(a.x,w0,acc[ii]); acc[ii]=fmaf(a.y,wq,acc[ii]); acc[ii]=fmaf(a.z,wz,acc[ii]); acc[ii]=fmaf(a.w,ww,acc[ii]);
      }
    }
    #pragma unroll
    for (int ii=0;ii<4;ii++) s_h[ib+ii][c] = ssilu_f(acc[ii]);
  }
  __syncthreads();
  {
    int c = t & 127;
    int ib = (t >> 7) * 4;
    float acc[4];
    float bv = bu2[c];
    #pragma unroll
    for (int ii=0;ii<4;ii++) acc[ii]=bv;
    for (int k=0;k<128;k+=4){
      float w0=wu2[(k+0)*128+c], wq=wu2[(k+1)*128+c], wz=wu2[(k+2)*128+c], ww=wu2[(k+3)*128+c];
      #pragma unroll
      for (int ii=0;ii<4;ii++){
        float4 a = *(const float4*)&s_h[ib+ii][k];
        acc[ii]=fmaf(a.x,w0,acc[ii]); acc[ii]=fmaf(a.y,wq,acc[ii]); acc[ii]=fmaf(a.z,wz,acc[ii]); acc[ii]=fmaf(a.w,ww,acc[ii]);
      }
    }
    #pragma unroll
    for (int ii=0;ii<4;ii++) s_h2[ib+ii][c] = acc[ii];
  }
  __syncthreads();
  {
    int c = t & 63;
    int gb = t >> 6;
    #pragma unroll
    for (int u=0;u<2;u++){
      int i = gb + 4*u;
      fx[(size_t)(n0+i)*64 + c] = ssilu_f(s_h2[i][c]);
      float xv = s_h2[i][64+c];
      #pragma unroll
      for (int cd=0;cd<3;cd++)
        fv[(size_t)(n0+i)*192 + cd*64 + c] = xv * s_v2[i][cd*64+c];
    }
  }
}

// ---------------- final: gated block 2 -> forces
__global__ __launch_bounds__(256) void k_final2(
    const float* __restrict__ fx, const float* __restrict__ fv,
    const float* __restrict__ wv1, const float* __restrict__ wv2,
    const float* __restrict__ wu1, const float* __restrict__ bu1,
    const float* __restrict__ wu2, const float* __restrict__ bu2,
    float* __restrict__ out)
{
  int t = threadIdx.x;
  int lane = t & 63;
  int n = blockIdx.x * 4 + (t >> 6);
  float fxv = fx[(size_t)n*64 + lane];
  float f0 = fv[(size_t)n*192 + lane];
  float f1 = fv[(size_t)n*192 + 64 + lane];
  float f2 = fv[(size_t)n*192 + 128 + lane];
  float a0=0.f, a1=0.f, a2=0.f;
  for (int k=0;k<64;k++){
    float w = wv1[k*64 + lane];
    a0 = fmaf(bcast(f0,k), w, a0);
    a1 = fmaf(bcast(f1,k), w, a1);
    a2 = fmaf(bcast(f2,k), w, a2);
  }
  float n1 = sqrtf(a0*a0 + a1*a1 + a2*a2);
  float w2v = wv2[lane];
  float r0 = f0*w2v, r1 = f1*w2v, r2 = f2*w2v;
  #pragma unroll
  for (int off=32; off>0; off>>=1){
    r0 += __shfl_xor(r0, off, 64);
    r1 += __shfl_xor(r1, off, 64);
    r2 += __shfl_xor(r2, off, 64);
  }
  float acc = bu1[lane];
  for (int k=0;k<64;k++) acc = fmaf(bcast(fxv,k), wu1[k*64+lane], acc);
  for (int k=0;k<64;k++) acc = fmaf(bcast(n1,k), wu1[(64+k)*64+lane], acc);
  float hv = ssilu_f(acc);
  float s1 = hv * wu2[lane*2 + 1];
  #pragma unroll
  for (int off=32; off>0; off>>=1) s1 += __shfl_xor(s1, off, 64);
  float h2_1 = s1 + bu2[1];
  if (lane == 0){
    out[(size_t)n*4 + 1] = h2_1 * r0;
    out[(size_t)n*4 + 2] = h2_1 * r1;
    out[(size_t)n*4 + 3] = h2_1 * r2;
  }
}

extern "C" void kernel_launch(void* const* d_in, const int* in_sizes, int n_in,
                              void* d_out, int out_size, void* d_ws, size_t ws_size,
                              hipStream_t stream)
{
  const float* x_in   = (const float*)d_in[0];
  const float* vec_in = (const float*)d_in[1];
  const int*   eidx   = (const int*)d_in[2];
  const float* erbf   = (const float*)d_in[3];
  const float* evec   = (const float*)d_in[4];
  const float* ln_w  = (const float*)d_in[5];
  const float* ln_b  = (const float*)d_in[6];
  const float* xp1_w = (const float*)d_in[7];
  const float* xp1_b = (const float*)d_in[8];
  const float* xp2_w = (const float*)d_in[9];
  const float* xp2_b = (const float*)d_in[10];
  const float* rbf_w = (const float*)d_in[11];
  const float* rbf_b = (const float*)d_in[12];
  const float* vp_w  = (const float*)d_in[13];
  const float* xv1_w = (const float*)d_in[14];
  const float* xv1_b = (const float*)d_in[15];
  const float* xv2_w = (const float*)d_in[16];
  const float* xv2_b = (const float*)d_in[17];
  const float* we1 = (const float*)d_in[18];
  const float* be1 = (const float*)d_in[19];
  const float* we2 = (const float*)d_in[20];
  const float* be2 = (const float*)d_in[21];
  const float* g1_v1 = (const float*)d_in[22];
  const float* g1_v2 = (const float*)d_in[23];
  const float* g1_u1 = (const float*)d_in[24];
  const float* g1_u1b = (const float*)d_in[25];
  const float* g1_u2 = (const float*)d_in[26];
  const float* g1_u2b = (const float*)d_in[27];
  const float* g2_v1 = (const float*)d_in[28];
  const float* g2_v2 = (const float*)d_in[29];
  const float* g2_u1 = (const float*)d_in[30];
  const float* g2_u1b = (const float*)d_in[31];
  const float* g2_u2 = (const float*)d_in[32];
  const float* g2_u2b = (const float*)d_in[33];
  float* out = (float*)d_out;

  float* ws = (float*)d_ws;
  float* x_cur   = ws;                       // N*128
  float* vec_cur = x_cur + (size_t)NN*128;   // N*384
  float* dx      = vec_cur + (size_t)NN*384; // N*128
  float* dvec    = dx + (size_t)NN*128;      // N*384
  float* xh      = dvec + (size_t)NN*384;    // N*384
  float* fxb     = xh;                       // N*64 (reuse during final)
  float* fvb     = xh + (size_t)NN*64;       // N*192
  int* eord      = (int*)(xh + (size_t)NN*384); // E
  int* off       = eord + EE;                // N+1
  unsigned* wpk  = (unsigned*)(off + NN + 1);// 6*64*192
  // cnt/cur alias the dx region (only used before layer 0 writes dx)
  int* cnt = (int*)dx;
  int* cur = cnt + NN;

  hipMemcpyAsync(x_cur, x_in, sizeof(float)*(size_t)NN*128, hipMemcpyDeviceToDevice, stream);
  hipMemcpyAsync(vec_cur, vec_in, sizeof(float)*(size_t)NN*384, hipMemcpyDeviceToDevice, stream);

  const int* esrc = eidx;
  const int* edst = eidx + EE;

  // CSR build (per call; deterministic up to within-node order)
  hipMemsetAsync(cnt, 0, sizeof(int)*NN, stream);
  k_hist<<<(EE+255)/256, 256, 0, stream>>>(edst, cnt);
  k_scan<<<1, 1024, 0, stream>>>(cnt, off, cur);
  k_fill<<<(EE+255)/256, 256, 0, stream>>>(edst, cur, eord);
  k_cvtw<<<(LL*64*192+255)/256, 256, 0, stream>>>(rbf_w, wpk);

  for (int l = 0; l < LL; l++){
    k_xh<<<NN/16, 256, 0, stream>>>(x_cur, ln_w + l*128, ln_b + l*128,
        xp1_w + (size_t)l*128*128, xp1_b + l*128,
        xp2_w + (size_t)l*128*384, xp2_b + l*384, xh);
    k_edge2<<<1024, 256, 0, stream>>>(wpk + (size_t)l*64*192, rbf_b + l*384,
        erbf, esrc, eord, off, evec, xh, vec_cur, dx, dvec);
    k_node<<<NN/8, 256, 0, stream>>>(vp_w + (size_t)l*128*256,
        xv1_w + (size_t)l*256*128, xv1_b + l*128,
        xv2_w + (size_t)l*128*384, xv2_b + l*384,
        dx, dvec, x_cur, vec_cur);
  }
  k_final1<<<NN/8, 256, 0, stream>>>(x_cur, vec_cur, we1, be1, we2, be2,
      g1_v1, g1_v2, g1_u1, g1_u1b, g1_u2, g1_u2b, out, fxb, fvb);
  k_final2<<<NN/4, 256, 0, stream>>>(fxb, fvb, g2_v1, g2_v2, g2_u1, g2_u1b, g2_u2, g2_u2b, out);
}

// Round 3
// 1587.340 us; speedup vs baseline: 1.7111x; 1.4098x over previous
//
#include <hip/hip_runtime.h>
#include <hip/hip_bf16.h>

#define NN 10000
#define EE 160000
#define LL 6

#define INV_SQRT_3f  0.57735026919f
#define INV_SQRT_Hf  0.08838834764832f
#define INV_SQRT_2f  0.70710678118655f

typedef _Float16 half8 __attribute__((ext_vector_type(8)));
typedef float f32x4 __attribute__((ext_vector_type(4)));

__device__ __forceinline__ float ssilu_f(float v){
  float s = 1.0f / (1.0f + __expf(-v));
  return v * s * 1.6666666666667f;
}
__device__ __forceinline__ float bcast(float v, int l){
  return __int_as_float(__builtin_amdgcn_readlane(__float_as_int(v), l));
}

// ---------------- CSR build ----------------
__global__ __launch_bounds__(256) void k_hist(const int* __restrict__ edst, int* __restrict__ cnt){
  int i = blockIdx.x*256 + threadIdx.x;
  if (i < EE) atomicAdd(&cnt[edst[i]], 1);
}

__global__ __launch_bounds__(1024) void k_scan(const int* __restrict__ cnt,
                                               int* __restrict__ off, int* __restrict__ cur){
  __shared__ int ps[1024];
  int t = threadIdx.x;
  int base = t*10;
  int local[10];
  int s = 0;
  #pragma unroll
  for (int i=0;i<10;i++){
    int c = (base+i < NN) ? cnt[base+i] : 0;
    local[i] = s; s += c;
  }
  ps[t] = s;
  __syncthreads();
  for (int d=1; d<1024; d<<=1){
    int v = (t>=d) ? ps[t-d] : 0;
    __syncthreads();
    ps[t] += v;
    __syncthreads();
  }
  int pre = (t>0) ? ps[t-1] : 0;
  #pragma unroll
  for (int i=0;i<10;i++){
    int idx = base+i;
    if (idx < NN){ int o = pre + local[i]; off[idx]=o; cur[idx]=o; }
  }
  if (t==1023) off[NN] = ps[1023];
}

__global__ __launch_bounds__(256) void k_fill(const int* __restrict__ edst,
                                              int* __restrict__ cur, int* __restrict__ eord){
  int i = blockIdx.x*256 + threadIdx.x;
  if (i < EE){
    int d = edst[i];
    int p = atomicAdd(&cur[d], 1);
    eord[p] = i;
  }
}

// ---------------- pack rbf_w into f16 MFMA B-fragment layout ----------------
// wf[(((l*24+nb)*2+kh)*64+lane)*8 + j] = w[l][k][ch]*scale,
//   k = 32*kh + 8*(lane>>4) + j, ch = nb*16 + (lane&15)
__global__ __launch_bounds__(256) void k_packw(const float* __restrict__ w, _Float16* __restrict__ wf){
  int i = blockIdx.x*256 + threadIdx.x;
  if (i >= LL*24*2*64*8) return;
  int j    = i & 7;
  int lane = (i >> 3) & 63;
  int kh   = (i >> 9) & 1;
  int rest = i >> 10;          // l*24 + nb
  int nb   = rest % 24;
  int l    = rest / 24;
  int k    = 32*kh + 8*(lane>>4) + j;
  int ch   = nb*16 + (lane&15);
  float v = w[((size_t)l*64 + k)*384 + ch];
  if (ch >= 128 && ch < 256) v *= INV_SQRT_3f;
  wf[i] = (_Float16)v;
}

__global__ __launch_bounds__(256) void k_packb(const float* __restrict__ b, float* __restrict__ bsc){
  int i = blockIdx.x*256 + threadIdx.x;
  if (i >= LL*384) return;
  int ch = i % 384;
  float v = b[i];
  if (ch >= 128 && ch < 256) v *= INV_SQRT_3f;
  bsc[i] = v;
}

// ---------------- rbfh GEMM: one wave per 16-edge tile (eord order) ----------------
__global__ __launch_bounds__(64) void k_gemm_rbfh(
    const float* __restrict__ erbf, const _Float16* __restrict__ wf,
    const float* __restrict__ bsc, const int* __restrict__ eord,
    _Float16* __restrict__ rbfh)
{
  int lane = threadIdx.x;
  int tile = blockIdx.x;
  int i0 = tile * 16;
  int mlane = lane & 15, kg = lane >> 4;
  int e_m = eord[i0 + mlane];
  const float* ar = erbf + (size_t)e_m*64 + 8*kg;
  half8 a0, a1;
  {
    float4 p0 = *(const float4*)(ar);
    float4 p1 = *(const float4*)(ar+4);
    a0[0]=(_Float16)p0.x; a0[1]=(_Float16)p0.y; a0[2]=(_Float16)p0.z; a0[3]=(_Float16)p0.w;
    a0[4]=(_Float16)p1.x; a0[5]=(_Float16)p1.y; a0[6]=(_Float16)p1.z; a0[7]=(_Float16)p1.w;
    float4 p2 = *(const float4*)(ar+32);
    float4 p3 = *(const float4*)(ar+36);
    a1[0]=(_Float16)p2.x; a1[1]=(_Float16)p2.y; a1[2]=(_Float16)p2.z; a1[3]=(_Float16)p2.w;
    a1[4]=(_Float16)p3.x; a1[5]=(_Float16)p3.y; a1[6]=(_Float16)p3.z; a1[7]=(_Float16)p3.w;
  }
  #pragma unroll 4
  for (int nb = 0; nb < 24; nb++){
    half8 b0 = *(const half8*)(wf + ((size_t)(nb*2+0)*64 + lane)*8);
    half8 b1 = *(const half8*)(wf + ((size_t)(nb*2+1)*64 + lane)*8);
    float bias = bsc[nb*16 + mlane];
    f32x4 acc = {bias, bias, bias, bias};
    acc = __builtin_amdgcn_mfma_f32_16x16x32_f16(a0, b0, acc, 0, 0, 0);
    acc = __builtin_amdgcn_mfma_f32_16x16x32_f16(a1, b1, acc, 0, 0, 0);
    _Float16* orow = rbfh + (size_t)i0*384 + nb*16 + mlane;
    #pragma unroll
    for (int r = 0; r < 4; r++)
      orow[(size_t)(kg*4 + r)*384] = (_Float16)acc[r];
  }
}

// ---------------- xh = ssilu(lnorm(x)@xp1+b)@xp2+b   (16 nodes / 256-thr block)
__global__ __launch_bounds__(256) void k_xh(
    const float* __restrict__ x,
    const float* __restrict__ lnw, const float* __restrict__ lnb,
    const float* __restrict__ w1, const float* __restrict__ b1,
    const float* __restrict__ w2, const float* __restrict__ b2,
    float* __restrict__ xh)
{
  __shared__ __align__(16) float s_xn[16][128];
  __shared__ __align__(16) float s_h1[16][128];
  int t = threadIdx.x;
  int n0 = blockIdx.x * 16;
  {
    int r = t >> 4, cc = t & 15;
    const float* xr = x + (size_t)(n0 + r) * 128;
    float v[8];
    float s = 0.f, ss = 0.f;
    #pragma unroll
    for (int u = 0; u < 8; u++){
      v[u] = xr[cc + 16*u];
      s += v[u]; ss += v[u]*v[u];
    }
    #pragma unroll
    for (int off = 8; off > 0; off >>= 1){
      s  += __shfl_xor(s, off, 16);
      ss += __shfl_xor(ss, off, 16);
    }
    float mean = s * (1.0f/128.0f);
    float var  = ss * (1.0f/128.0f) - mean*mean;
    float rstd = rsqrtf(var + 1e-5f);
    #pragma unroll
    for (int u = 0; u < 8; u++){
      int h = cc + 16*u;
      s_xn[r][h] = (v[u] - mean) * rstd * lnw[h] + lnb[h];
    }
  }
  __syncthreads();
  {
    int c = t & 127;
    int rb = t >> 7;
    float acc[8];
    float bv = b1[c];
    #pragma unroll
    for (int u = 0; u < 8; u++) acc[u] = bv;
    for (int k = 0; k < 128; k += 4){
      float w0 = w1[(k+0)*128 + c];
      float wq = w1[(k+1)*128 + c];
      float wz = w1[(k+2)*128 + c];
      float ww = w1[(k+3)*128 + c];
      #pragma unroll
      for (int u = 0; u < 8; u++){
        float4 xv = *(const float4*)&s_xn[rb + 2*u][k];
        acc[u] = fmaf(xv.x, w0, acc[u]);
        acc[u] = fmaf(xv.y, wq, acc[u]);
        acc[u] = fmaf(xv.z, wz, acc[u]);
        acc[u] = fmaf(xv.w, ww, acc[u]);
      }
    }
    #pragma unroll
    for (int u = 0; u < 8; u++) s_h1[rb + 2*u][c] = ssilu_f(acc[u]);
  }
  __syncthreads();
  {
    int c = t & 127;
    int rb = t >> 7;
    float a0[8], a1[8], a2[8];
    float bb0 = b2[c], bb1 = b2[c+128], bb2 = b2[c+256];
    #pragma unroll
    for (int u=0;u<8;u++){ a0[u]=bb0; a1[u]=bb1; a2[u]=bb2; }
    for (int k = 0; k < 128; k += 4){
      float wa[4], wb[4], wc[4];
      #pragma unroll
      for (int j=0;j<4;j++){
        const float* wr = w2 + (size_t)(k+j)*384;
        wa[j]=wr[c]; wb[j]=wr[c+128]; wc[j]=wr[c+256];
      }
      #pragma unroll
      for (int u = 0; u < 8; u++){
        float4 hv = *(const float4*)&s_h1[rb + 2*u][k];
        a0[u]=fmaf(hv.x,wa[0],a0[u]); a0[u]=fmaf(hv.y,wa[1],a0[u]); a0[u]=fmaf(hv.z,wa[2],a0[u]); a0[u]=fmaf(hv.w,wa[3],a0[u]);
        a1[u]=fmaf(hv.x,wb[0],a1[u]); a1[u]=fmaf(hv.y,wb[1],a1[u]); a1[u]=fmaf(hv.z,wb[2],a1[u]); a1[u]=fmaf(hv.w,wb[3],a1[u]);
        a2[u]=fmaf(hv.x,wc[0],a2[u]); a2[u]=fmaf(hv.y,wc[1],a2[u]); a2[u]=fmaf(hv.z,wc[2],a2[u]); a2[u]=fmaf(hv.w,wc[3],a2[u]);
      }
    }
    #pragma unroll
    for (int u = 0; u < 8; u++){
      float* o = xh + (size_t)(n0 + rb + 2*u) * 384;
      o[c] = a0[u]; o[c+128] = a1[u]; o[c+256] = a2[u];
    }
  }
}

// ---------------- edge kernel, dst-side, no atomics, no GEMV: one wave per dst node
__global__ __launch_bounds__(256) void k_edge3(
    const _Float16* __restrict__ rbfh,
    const int* __restrict__ esrc,
    const int* __restrict__ eord, const int* __restrict__ off,
    const float* __restrict__ evec,
    const float* __restrict__ xh, const float* __restrict__ vec,
    float* __restrict__ dx, float* __restrict__ dvec)
{
  int t = threadIdx.x;
  int lane = t & 63;
  int n = blockIdx.x*4 + (t>>6);
  if (n >= NN) return;
  int o0 = off[n], o1 = off[n+1];
  float ax0 = 0.f, ax1 = 0.f;
  float av00=0.f, av01=0.f, av10=0.f, av11=0.f, av20=0.f, av21=0.f;
  #pragma unroll 2
  for (int p = o0; p < o1; p++){
    int eid = eord[p];
    const _Float16* hr = rbfh + (size_t)p*384;
    float h0 = (float)hr[lane];
    float h1 = (float)hr[64+lane];
    float h2 = (float)hr[128+lane];
    float h3 = (float)hr[192+lane];
    float h4 = (float)hr[256+lane];
    float h5 = (float)hr[320+lane];
    int sN = esrc[eid];
    const float* xr = xh + (size_t)sN*384;
    float m0  = h0 * xr[lane];
    float m1  = h1 * xr[64+lane];
    float m2a = h2 * xr[128+lane];
    float m2b = h3 * xr[192+lane];
    float m3a = h4 * xr[256+lane];
    float m3b = h5 * xr[320+lane];
    ax0 += m0; ax1 += m1;
    const float* vr = vec + (size_t)sN*384;
    float ev0 = evec[(size_t)eid*3 + 0];
    float ev1 = evec[(size_t)eid*3 + 1];
    float ev2 = evec[(size_t)eid*3 + 2];
    av00 = fmaf(vr[lane],     m2a, av00); av00 = fmaf(m3a, ev0, av00);
    av01 = fmaf(vr[64+lane],  m2b, av01); av01 = fmaf(m3b, ev0, av01);
    av10 = fmaf(vr[128+lane], m2a, av10); av10 = fmaf(m3a, ev1, av10);
    av11 = fmaf(vr[192+lane], m2b, av11); av11 = fmaf(m3b, ev1, av11);
    av20 = fmaf(vr[256+lane], m2a, av20); av20 = fmaf(m3a, ev2, av20);
    av21 = fmaf(vr[320+lane], m2b, av21); av21 = fmaf(m3b, ev2, av21);
  }
  float* dxr = dx + (size_t)n*128;
  dxr[lane] = ax0; dxr[64+lane] = ax1;
  float* dvr = dvec + (size_t)n*384;
  dvr[lane]     = av00 * INV_SQRT_Hf;
  dvr[64+lane]  = av01 * INV_SQRT_Hf;
  dvr[128+lane] = av10 * INV_SQRT_Hf;
  dvr[192+lane] = av11 * INV_SQRT_Hf;
  dvr[256+lane] = av20 * INV_SQRT_Hf;
  dvr[320+lane] = av21 * INV_SQRT_Hf;
}

// ---------------- node update: x,vec += agg; vp; vec_dot/vnorm; xv MLP; final (8 nodes/block)
__global__ __launch_bounds__(256) void k_node(
    const float* __restrict__ vp_w,
    const float* __restrict__ xv1_w, const float* __restrict__ xv1_b,
    const float* __restrict__ xv2_w, const float* __restrict__ xv2_b,
    const float* __restrict__ dx, const float* __restrict__ dvec,
    float* __restrict__ x, float* __restrict__ vec)
{
  __shared__ __align__(16) float s_xn[8][128];
  __shared__ __align__(16) float s_vl[8][384];
  __shared__ __align__(16) float s_v1[8][384];
  __shared__ __align__(16) float s_v2[8][384];
  __shared__ __align__(16) float s_vd[8][128];
  __shared__ __align__(16) float s_vn[8][128];
  __shared__ __align__(16) float s_h1[8][128];
  int t = threadIdx.x;
  int n0 = blockIdx.x * 8;
  for (int idx = t; idx < 8*128; idx += 256){
    int i = idx >> 7, h = idx & 127;
    size_t p = (size_t)(n0+i)*128 + h;
    s_xn[i][h] = (x[p] + dx[p]) * INV_SQRT_2f;
  }
  for (int idx = t; idx < 8*384; idx += 256){
    int i = idx / 384, h = idx % 384;
    size_t p = (size_t)(n0+i)*384 + h;
    s_vl[i][h] = vec[p] + dvec[p];
  }
  __syncthreads();
  {
    int ob = t & 127;
    int ib = (t >> 7) * 4;
    float acc0[4][3], acc1[4][3];
    #pragma unroll
    for (int ii=0;ii<4;ii++){
      #pragma unroll
      for (int cd=0;cd<3;cd++){ acc0[ii][cd]=0.f; acc1[ii][cd]=0.f; }
    }
    for (int k = 0; k < 128; k += 4){
      float wA[4], wB[4];
      #pragma unroll
      for (int j=0;j<4;j++){
        const float* wr = vp_w + (size_t)(k+j)*256;
        wA[j] = wr[ob]; wB[j] = wr[ob+128];
      }
      #pragma unroll
      for (int ii = 0; ii < 4; ii++){
        #pragma unroll
        for (int cd = 0; cd < 3; cd++){
          float4 a = *(const float4*)&s_vl[ib+ii][cd*128 + k];
          float s0 = acc0[ii][cd], s1 = acc1[ii][cd];
          s0 = fmaf(a.x, wA[0], s0); s0 = fmaf(a.y, wA[1], s0); s0 = fmaf(a.z, wA[2], s0); s0 = fmaf(a.w, wA[3], s0);
          s1 = fmaf(a.x, wB[0], s1); s1 = fmaf(a.y, wB[1], s1); s1 = fmaf(a.z, wB[2], s1); s1 = fmaf(a.w, wB[3], s1);
          acc0[ii][cd] = s0; acc1[ii][cd] = s1;
        }
      }
    }
    #pragma unroll
    for (int ii = 0; ii < 4; ii++){
      #pragma unroll
      for (int cd = 0; cd < 3; cd++){
        s_v1[ib+ii][cd*128 + ob] = acc0[ii][cd];
        s_v2[ib+ii][cd*128 + ob] = acc1[ii][cd];
      }
    }
  }
  __syncthreads();
  #pragma unroll
  for (int rep = 0; rep < 4; rep++){
    int idx = rep*256 + t;
    int i = idx >> 7, h = idx & 127;
    float a0 = s_v1[i][h],     b0 = s_v2[i][h];
    float a1 = s_v1[i][128+h], b1 = s_v2[i][128+h];
    float a2 = s_v1[i][256+h], b2 = s_v2[i][256+h];
    s_vd[i][h] = (a0*b0 + a1*b1 + a2*b2) * INV_SQRT_Hf;
    s_vn[i][h] = sqrtf(b0*b0 + b1*b1 + b2*b2 + 1e-8f);
  }
  __syncthreads();
  {
    int c = t & 127;
    int ib = (t >> 7) * 4;
    float acc[4];
    float bv = xv1_b[c];
    #pragma unroll
    for (int ii=0;ii<4;ii++) acc[ii]=bv;
    for (int k = 0; k < 128; k += 4){
      float w0 = xv1_w[(k+0)*128+c], wq = xv1_w[(k+1)*128+c], wz = xv1_w[(k+2)*128+c], ww = xv1_w[(k+3)*128+c];
      #pragma unroll
      for (int ii=0;ii<4;ii++){
        float4 a = *(const float4*)&s_xn[ib+ii][k];
        acc[ii]=fmaf(a.x,w0,acc[ii]); acc[ii]=fmaf(a.y,wq,acc[ii]); acc[ii]=fmaf(a.z,wz,acc[ii]); acc[ii]=fmaf(a.w,ww,acc[ii]);
      }
    }
    for (int k = 0; k < 128; k += 4){
      float w0 = xv1_w[(128+k+0)*128+c], wq = xv1_w[(128+k+1)*128+c], wz = xv1_w[(128+k+2)*128+c], ww = xv1_w[(128+k+3)*128+c];
      #pragma unroll
      for (int ii=0;ii<4;ii++){
        float4 a = *(const float4*)&s_vn[ib+ii][k];
        acc[ii]=fmaf(a.x,w0,acc[ii]); acc[ii]=fmaf(a.y,wq,acc[ii]); acc[ii]=fmaf(a.z,wz,acc[ii]); acc[ii]=fmaf(a.w,ww,acc[ii]);
      }
    }
    #pragma unroll
    for (int ii=0;ii<4;ii++) s_h1[ib+ii][c] = ssilu_f(acc[ii]);
  }
  __syncthreads();
  {
    int c = t & 127;
    int ib = (t >> 7) * 4;
    float a0[4], a1[4], a2[4];
    float bb0 = xv2_b[c], bb1 = xv2_b[c+128], bb2 = xv2_b[c+256];
    #pragma unroll
    for (int ii=0;ii<4;ii++){ a0[ii]=bb0; a1[ii]=bb1; a2[ii]=bb2; }
    for (int k = 0; k < 128; k += 4){
      float wa[4], wb[4], wc[4];
      #pragma unroll
      for (int j=0;j<4;j++){
        const float* wr = xv2_w + (size_t)(k+j)*384;
        wa[j]=wr[c]; wb[j]=wr[c+128]; wc[j]=wr[c+256];
      }
      #pragma unroll
      for (int ii=0;ii<4;ii++){
        float4 h4 = *(const float4*)&s_h1[ib+ii][k];
        a0[ii]=fmaf(h4.x,wa[0],a0[ii]); a0[ii]=fmaf(h4.y,wa[1],a0[ii]); a0[ii]=fmaf(h4.z,wa[2],a0[ii]); a0[ii]=fmaf(h4.w,wa[3],a0[ii]);
        a1[ii]=fmaf(h4.x,wb[0],a1[ii]); a1[ii]=fmaf(h4.y,wb[1],a1[ii]); a1[ii]=fmaf(h4.z,wb[2],a1[ii]); a1[ii]=fmaf(h4.w,wb[3],a1[ii]);
        a2[ii]=fmaf(h4.x,wc[0],a2[ii]); a2[ii]=fmaf(h4.y,wc[1],a2[ii]); a2[ii]=fmaf(h4.z,wc[2],a2[ii]); a2[ii]=fmaf(h4.w,wc[3],a2[ii]);
      }
    }
    #pragma unroll
    for (int ii=0;ii<4;ii++){
      int i = ib+ii;
      s_v2[i][c] = a0[ii]; s_v2[i][c+128] = a1[ii]; s_v2[i][c+256] = a2[ii];
    }
  }
  __syncthreads();
  #pragma unroll
  for (int rep = 0; rep < 4; rep++){
    int idx = rep*256 + t;
    int i = idx >> 7, h = idx & 127;
    float xout = s_xn[i][h] + (s_v2[i][h] + s_v2[i][128+h]*s_vd[i][h]) * INV_SQRT_2f;
    x[(size_t)(n0+i)*128 + h] = xout;
  }
  for (int idx = t; idx < 8*384; idx += 256){
    int i = idx / 384, r = idx % 384;
    int h = r & 127;
    vec[(size_t)(n0+i)*384 + r] = s_vl[i][r] + s_v2[i][256+h] * s_v1[i][r];
  }
}

// ---------------- final: energy + gated block 1 (8 nodes / block)
__global__ __launch_bounds__(256) void k_final1(
    const float* __restrict__ x, const float* __restrict__ vec,
    const float* __restrict__ we1, const float* __restrict__ be1,
    const float* __restrict__ we2, const float* __restrict__ be2,
    const float* __restrict__ wv1, const float* __restrict__ wv2,
    const float* __restrict__ wu1, const float* __restrict__ bu1,
    const float* __restrict__ wu2, const float* __restrict__ bu2,
    float* __restrict__ out, float* __restrict__ fx, float* __restrict__ fv)
{
  __shared__ __align__(16) float s_x[8][128];
  __shared__ __align__(16) float s_vl[8][384];
  __shared__ __align__(16) float s_p[8][384];
  __shared__ __align__(16) float s_n1[8][128];
  __shared__ __align__(16) float s_v2[8][192];
  __shared__ __align__(16) float s_h[8][128];
  __shared__ __align__(16) float s_h2[8][128];
  __shared__ __align__(16) float s_e1[8][64];
  int t = threadIdx.x;
  int n0 = blockIdx.x * 8;
  for (int idx = t; idx < 8*128; idx += 256){
    int i = idx >> 7, h = idx & 127;
    s_x[i][h] = x[(size_t)(n0+i)*128 + h];
  }
  for (int idx = t; idx < 8*384; idx += 256){
    int i = idx / 384, h = idx % 384;
    s_vl[i][h] = vec[(size_t)(n0+i)*384 + h];
  }
  __syncthreads();
  {
    int c = t & 63;
    int gb = t >> 6;
    #pragma unroll
    for (int u = 0; u < 2; u++){
      int i = gb + 4*u;
      float acc = be1[c];
      for (int k = 0; k < 128; k += 4){
        float w0 = we1[(k+0)*64+c], wq = we1[(k+1)*64+c], wz = we1[(k+2)*64+c], ww = we1[(k+3)*64+c];
        float4 a = *(const float4*)&s_x[i][k];
        acc = fmaf(a.x,w0,acc); acc=fmaf(a.y,wq,acc); acc=fmaf(a.z,wz,acc); acc=fmaf(a.w,ww,acc);
      }
      s_e1[i][c] = ssilu_f(acc);
    }
  }
  __syncthreads();
  {
    int lane = t & 63;
    int gb = t >> 6;
    #pragma unroll
    for (int u = 0; u < 2; u++){
      int i = gb + 4*u;
      float v = s_e1[i][lane] * we2[lane];
      #pragma unroll
      for (int off = 32; off > 0; off >>= 1) v += __shfl_xor(v, off, 64);
      if (lane == 0) out[(size_t)(n0+i)*4 + 0] = v + be2[0];
    }
  }
  {
    int ob = t & 127;
    int ib = (t >> 7) * 4;
    float acc[4][3];
    #pragma unroll
    for (int ii=0;ii<4;ii++){
      #pragma unroll
      for (int cd=0;cd<3;cd++) acc[ii][cd]=0.f;
    }
    for (int k = 0; k < 128; k += 4){
      float w0 = wv1[(k+0)*128+ob], wq=wv1[(k+1)*128+ob], wz=wv1[(k+2)*128+ob], ww=wv1[(k+3)*128+ob];
      #pragma unroll
      for (int ii=0;ii<4;ii++){
        #pragma unroll
        for (int cd=0;cd<3;cd++){
          float4 a = *(const float4*)&s_vl[ib+ii][cd*128+k];
          float s0=acc[ii][cd];
          s0=fmaf(a.x,w0,s0); s0=fmaf(a.y,wq,s0); s0=fmaf(a.z,wz,s0); s0=fmaf(a.w,ww,s0);
          acc[ii][cd]=s0;
        }
      }
    }
    #pragma unroll
    for (int ii=0;ii<4;ii++){
      #pragma unroll
      for (int cd=0;cd<3;cd++) s_p[ib+ii][cd*128+ob] = acc[ii][cd];
    }
  }
  __syncthreads();
  #pragma unroll
  for (int rep = 0; rep < 4; rep++){
    int idx = rep*256+t;
    int i = idx >> 7, h = idx & 127;
    float p0 = s_p[i][h], p1 = s_p[i][128+h], p2 = s_p[i][256+h];
    s_n1[i][h] = sqrtf(p0*p0 + p1*p1 + p2*p2);
  }
  {
    int c = t & 63;
    int gb = t >> 6;
    float acc[2][3];
    #pragma unroll
    for (int u=0;u<2;u++){
      #pragma unroll
      for (int cd=0;cd<3;cd++) acc[u][cd]=0.f;
    }
    for (int k=0;k<128;k+=4){
      float w0=wv2[(k+0)*64+c], wq=wv2[(k+1)*64+c], wz=wv2[(k+2)*64+c], ww=wv2[(k+3)*64+c];
      #pragma unroll
      for (int u=0;u<2;u++){
        int i = gb + 4*u;
        #pragma unroll
        for (int cd=0;cd<3;cd++){
          float4 a = *(const float4*)&s_vl[i][cd*128+k];
          float s0=acc[u][cd];
          s0=fmaf(a.x,w0,s0); s0=fmaf(a.y,wq,s0); s0=fmaf(a.z,wz,s0); s0=fmaf(a.w,ww,s0);
          acc[u][cd]=s0;
        }
      }
    }
    #pragma unroll
    for (int u=0;u<2;u++){
      int i=gb+4*u;
      #pragma unroll
      for (int cd=0;cd<3;cd++) s_v2[i][cd*64+c]=acc[u][cd];
    }
  }
  __syncthreads();
  {
    int c = t & 127;
    int ib = (t >> 7) * 4;
    float acc[4];
    float bv = bu1[c];
    #pragma unroll
    for (int ii=0;ii<4;ii++) acc[ii]=bv;
    for (int k=0;k<128;k+=4){
      float w0=wu1[(k+0)*128+c], wq=wu1[(k+1)*128+c], wz=wu1[(k+2)*128+c], ww=wu1[(k+3)*128+c];
      #pragma unroll
      for (int ii=0;ii<4;ii++){
        float4 a = *(const float4*)&s_x[ib+ii][k];
        acc[ii]=fmaf(a.x,w0,acc[ii]); acc[ii]=fmaf(a.y,wq,acc[ii]); acc[ii]=fmaf(a.z,wz,acc[ii]); acc[ii]=fmaf(a.w,ww,acc[ii]);
      }
    }
    for (int k=0;k<128;k+=4){
      float w0=wu1[(128+k+0)*128+c], wq=wu1[(128+k+1)*128+c], wz=wu1[(128+k+2)*128+c], ww=wu1[(128+k+3)*128+c];
      #pragma unroll
      for (int ii=0;ii<4;ii++){
        float4 a = *(const float4*)&s_n1[ib+ii][k];
        acc[ii]=fmaf(a.x,w0,acc[ii]); acc[ii]=fmaf(a.y,wq,acc[ii]); acc[ii]=fmaf(a.z,wz,acc[ii]); acc[ii]=fmaf(a.w,ww,acc[ii]);
      }
    }
    #pragma unroll
    for (int ii=0;ii<4;ii++) s_h[ib+ii][c] = ssilu_f(acc[ii]);
  }
  __syncthreads();
  {
    int c = t & 127;
    int ib = (t >> 7) * 4;
    float acc[4];
    float bv = bu2[c];
    #pragma unroll
    for (int ii=0;ii<4;ii++) acc[ii]=bv;
    for (int k=0;k<128;k+=4){
      float w0=wu2[(k+0)*128+c], wq=wu2[(k+1)*128+c], wz=wu2[(k+2)*128+c], ww=wu2[(k+3)*128+c];
      #pragma unroll
      for (int ii=0;ii<4;ii++){
        float4 a = *(const float4*)&s_h[ib+ii][k];
        acc[ii]=fmaf(a.x,w0,acc[ii]); acc[ii]=fmaf(a.y,wq,acc[ii]); acc[ii]=fmaf(a.z,wz,acc[ii]); acc[ii]=fmaf(a.w,ww,acc[ii]);
      }
    }
    #pragma unroll
    for (int ii=0;ii<4;ii++) s_h2[ib+ii][c] = acc[ii];
  }
  __syncthreads();
  {
    int c = t & 63;
    int gb = t >> 6;
    #pragma unroll
    for (int u=0;u<2;u++){
      int i = gb + 4*u;
      fx[(size_t)(n0+i)*64 + c] = ssilu_f(s_h2[i][c]);
      float xv = s_h2[i][64+c];
      #pragma unroll
      for (int cd=0;cd<3;cd++)
        fv[(size_t)(n0+i)*192 + cd*64 + c] = xv * s_v2[i][cd*64+c];
    }
  }
}

// ---------------- final: gated block 2 -> forces
__global__ __launch_bounds__(256) void k_final2(
    const float* __restrict__ fx, const float* __restrict__ fv,
    const float* __restrict__ wv1, const float* __restrict__ wv2,
    const float* __restrict__ wu1, const float* __restrict__ bu1,
    const float* __restrict__ wu2, const float* __restrict__ bu2,
    float* __restrict__ out)
{
  int t = threadIdx.x;
  int lane = t & 63;
  int n = blockIdx.x * 4 + (t >> 6);
  float fxv = fx[(size_t)n*64 + lane];
  float f0 = fv[(size_t)n*192 + lane];
  float f1 = fv[(size_t)n*192 + 64 + lane];
  float f2 = fv[(size_t)n*192 + 128 + lane];
  float a0=0.f, a1=0.f, a2=0.f;
  for (int k=0;k<64;k++){
    float w = wv1[k*64 + lane];
    a0 = fmaf(bcast(f0,k), w, a0);
    a1 = fmaf(bcast(f1,k), w, a1);
    a2 = fmaf(bcast(f2,k), w, a2);
  }
  float n1 = sqrtf(a0*a0 + a1*a1 + a2*a2);
  float w2v = wv2[lane];
  float r0 = f0*w2v, r1 = f1*w2v, r2 = f2*w2v;
  #pragma unroll
  for (int off=32; off>0; off>>=1){
    r0 += __shfl_xor(r0, off, 64);
    r1 += __shfl_xor(r1, off, 64);
    r2 += __shfl_xor(r2, off, 64);
  }
  float acc = bu1[lane];
  for (int k=0;k<64;k++) acc = fmaf(bcast(fxv,k), wu1[k*64+lane], acc);
  for (int k=0;k<64;k++) acc = fmaf(bcast(n1,k), wu1[(64+k)*64+lane], acc);
  float hv = ssilu_f(acc);
  float s1 = hv * wu2[lane*2 + 1];
  #pragma unroll
  for (int off=32; off>0; off>>=1) s1 += __shfl_xor(s1, off, 64);
  float h2_1 = s1 + bu2[1];
  if (lane == 0){
    out[(size_t)n*4 + 1] = h2_1 * r0;
    out[(size_t)n*4 + 2] = h2_1 * r1;
    out[(size_t)n*4 + 3] = h2_1 * r2;
  }
}

extern "C" void kernel_launch(void* const* d_in, const int* in_sizes, int n_in,
                              void* d_out, int out_size, void* d_ws, size_t ws_size,
                              hipStream_t stream)
{
  const float* x_in   = (const float*)d_in[0];
  const float* vec_in = (const float*)d_in[1];
  const int*   eidx   = (const int*)d_in[2];
  const float* erbf   = (const float*)d_in[3];
  const float* evec   = (const float*)d_in[4];
  const float* ln_w  = (const float*)d_in[5];
  const float* ln_b  = (const float*)d_in[6];
  const float* xp1_w = (const float*)d_in[7];
  const float* xp1_b = (const float*)d_in[8];
  const float* xp2_w = (const float*)d_in[9];
  const float* xp2_b = (const float*)d_in[10];
  const float* rbf_w = (const float*)d_in[11];
  const float* rbf_b = (const float*)d_in[12];
  const float* vp_w  = (const float*)d_in[13];
  const float* xv1_w = (const float*)d_in[14];
  const float* xv1_b = (const float*)d_in[15];
  const float* xv2_w = (const float*)d_in[16];
  const float* xv2_b = (const float*)d_in[17];
  const float* we1 = (const float*)d_in[18];
  const float* be1 = (const float*)d_in[19];
  const float* we2 = (const float*)d_in[20];
  const float* be2 = (const float*)d_in[21];
  const float* g1_v1 = (const float*)d_in[22];
  const float* g1_v2 = (const float*)d_in[23];
  const float* g1_u1 = (const float*)d_in[24];
  const float* g1_u1b = (const float*)d_in[25];
  const float* g1_u2 = (const float*)d_in[26];
  const float* g1_u2b = (const float*)d_in[27];
  const float* g2_v1 = (const float*)d_in[28];
  const float* g2_v2 = (const float*)d_in[29];
  const float* g2_u1 = (const float*)d_in[30];
  const float* g2_u1b = (const float*)d_in[31];
  const float* g2_u2 = (const float*)d_in[32];
  const float* g2_u2b = (const float*)d_in[33];
  float* out = (float*)d_out;

  char* base = (char*)d_ws;
  size_t o = 0;
  auto alloc = [&](size_t bytes) -> char* {
    char* p = base + o;
    o = (o + bytes + 255) & ~(size_t)255;
    return p;
  };
  float* x_cur   = (float*)alloc((size_t)NN*128*4);
  float* vec_cur = (float*)alloc((size_t)NN*384*4);
  float* dx      = (float*)alloc((size_t)NN*128*4);
  float* dvec    = (float*)alloc((size_t)NN*384*4);
  float* xh      = (float*)alloc((size_t)NN*384*4);
  int*   eord    = (int*)alloc((size_t)EE*4);
  int*   off     = (int*)alloc((size_t)(NN+1)*4);
  _Float16* wf   = (_Float16*)alloc((size_t)LL*24*2*64*8*2);
  float* bsc     = (float*)alloc((size_t)LL*384*4);
  _Float16* rbfh = (_Float16*)alloc((size_t)EE*384*2);
  float* fxb     = xh;                        // N*64 (reuse during final)
  float* fvb     = xh + (size_t)NN*64;        // N*192
  int* cnt = (int*)dx;                        // pre-layer-0 reuse
  int* cur = cnt + NN;

  hipMemcpyAsync(x_cur, x_in, sizeof(float)*(size_t)NN*128, hipMemcpyDeviceToDevice, stream);
  hipMemcpyAsync(vec_cur, vec_in, sizeof(float)*(size_t)NN*384, hipMemcpyDeviceToDevice, stream);

  const int* esrc = eidx;
  const int* edst = eidx + EE;

  hipMemsetAsync(cnt, 0, sizeof(int)*NN, stream);
  k_hist<<<(EE+255)/256, 256, 0, stream>>>(edst, cnt);
  k_scan<<<1, 1024, 0, stream>>>(cnt, off, cur);
  k_fill<<<(EE+255)/256, 256, 0, stream>>>(edst, cur, eord);
  k_packw<<<(LL*24*2*64*8+255)/256, 256, 0, stream>>>(rbf_w, wf);
  k_packb<<<(LL*384+255)/256, 256, 0, stream>>>(rbf_b, bsc);

  for (int l = 0; l < LL; l++){
    k_xh<<<NN/16, 256, 0, stream>>>(x_cur, ln_w + l*128, ln_b + l*128,
        xp1_w + (size_t)l*128*128, xp1_b + l*128,
        xp2_w + (size_t)l*128*384, xp2_b + l*384, xh);
    k_gemm_rbfh<<<EE/16, 64, 0, stream>>>(erbf, wf + (size_t)l*24*2*64*8,
        bsc + (size_t)l*384, eord, rbfh);
    k_edge3<<<NN/4, 256, 0, stream>>>(rbfh, esrc, eord, off, evec, xh, vec_cur, dx, dvec);
    k_node<<<NN/8, 256, 0, stream>>>(vp_w + (size_t)l*128*256,
        xv1_w + (size_t)l*256*128, xv1_b + l*128,
        xv2_w + (size_t)l*128*384, xv2_b + l*384,
        dx, dvec, x_cur, vec_cur);
  }
  k_final1<<<NN/8, 256, 0, stream>>>(x_cur, vec_cur, we1, be1, we2, be2,
      g1_v1, g1_v2, g1_u1, g1_u1b, g1_u2, g1_u2b, out, fxb, fvb);
  k_final2<<<NN/4, 256, 0, stream>>>(fxb, fvb, g2_v1, g2_v2, g2_u1, g2_u1b, g2_u2, g2_u2b, out);
}

// Round 4
// 1085.196 us; speedup vs baseline: 2.5029x; 1.4627x over previous
//
#include <hip/hip_runtime.h>
#include <hip/hip_bf16.h>

#define NN 10000
#define EE 160000
#define LL 6

#define INV_SQRT_3f  0.57735026919f
#define INV_SQRT_Hf  0.08838834764832f
#define INV_SQRT_2f  0.70710678118655f

typedef _Float16 half8 __attribute__((ext_vector_type(8)));
typedef float f32x4 __attribute__((ext_vector_type(4)));

__device__ __forceinline__ float ssilu_f(float v){
  float s = 1.0f / (1.0f + __expf(-v));
  return v * s * 1.6666666666667f;
}
__device__ __forceinline__ float bcast(float v, int l){
  return __int_as_float(__builtin_amdgcn_readlane(__float_as_int(v), l));
}

// ---------------- CSR build ----------------
__global__ __launch_bounds__(256) void k_hist(const int* __restrict__ edst, int* __restrict__ cnt){
  int i = blockIdx.x*256 + threadIdx.x;
  if (i < EE) atomicAdd(&cnt[edst[i]], 1);
}

__global__ __launch_bounds__(1024) void k_scan(const int* __restrict__ cnt,
                                               int* __restrict__ off, int* __restrict__ cur){
  __shared__ int ps[1024];
  int t = threadIdx.x;
  int base = t*10;
  int local[10];
  int s = 0;
  #pragma unroll
  for (int i=0;i<10;i++){
    int c = (base+i < NN) ? cnt[base+i] : 0;
    local[i] = s; s += c;
  }
  ps[t] = s;
  __syncthreads();
  for (int d=1; d<1024; d<<=1){
    int v = (t>=d) ? ps[t-d] : 0;
    __syncthreads();
    ps[t] += v;
    __syncthreads();
  }
  int pre = (t>0) ? ps[t-1] : 0;
  #pragma unroll
  for (int i=0;i<10;i++){
    int idx = base+i;
    if (idx < NN){ int o = pre + local[i]; off[idx]=o; cur[idx]=o; }
  }
  if (t==1023) off[NN] = ps[1023];
}

__global__ __launch_bounds__(256) void k_fill(const int* __restrict__ edst,
                                              int* __restrict__ cur, int* __restrict__ eord){
  int i = blockIdx.x*256 + threadIdx.x;
  if (i < EE){
    int d = edst[i];
    int p = atomicAdd(&cur[d], 1);
    eord[p] = i;
  }
}

// ---------------- pack rbf_w into f16 MFMA B-fragment layout (+ INV_SQRT_3 fold) ----------------
__global__ __launch_bounds__(256) void k_packw(const float* __restrict__ w, _Float16* __restrict__ wf){
  int i = blockIdx.x*256 + threadIdx.x;
  if (i >= LL*24*2*64*8) return;
  int j    = i & 7;
  int lane = (i >> 3) & 63;
  int kh   = (i >> 9) & 1;
  int rest = i >> 10;          // l*24 + nb
  int nb   = rest % 24;
  int l    = rest / 24;
  int k    = 32*kh + 8*(lane>>4) + j;
  int ch   = nb*16 + (lane&15);
  float v = w[((size_t)l*64 + k)*384 + ch];
  if (ch >= 128 && ch < 256) v *= INV_SQRT_3f;
  wf[i] = (_Float16)v;
}

__global__ __launch_bounds__(256) void k_packb(const float* __restrict__ b, float* __restrict__ bsc){
  int i = blockIdx.x*256 + threadIdx.x;
  if (i >= LL*384) return;
  int ch = i % 384;
  float v = b[i];
  if (ch >= 128 && ch < 256) v *= INV_SQRT_3f;
  bsc[i] = v;
}

// ---------------- generic pack: f32 [K][NO] -> f16 B-fragment order ----------------
struct PackTab {
  const float* s[30];
  _Float16* d[30];
  int K[30];
  int NO[30];
};
__global__ __launch_bounds__(256) void k_packall(PackTab tb){
  int e = blockIdx.y;
  int K = tb.K[e], NO = tb.NO[e];
  int tot = K*NO, KS = K >> 5;
  const float* s = tb.s[e];
  _Float16* d = tb.d[e];
  for (int i = blockIdx.x*256 + threadIdx.x; i < tot; i += gridDim.x*256){
    int j = i & 7, lane = (i >> 3) & 63, rest = i >> 9;
    int ks = rest % KS, nb = rest / KS;
    int k = ks*32 + (lane>>4)*8 + j, n = nb*16 + (lane&15);
    d[i] = (_Float16)s[(size_t)k*NO + n];
  }
}

__global__ __launch_bounds__(256) void k_cvt16(const float* __restrict__ v, _Float16* __restrict__ o, int n){
  int i = blockIdx.x*256 + threadIdx.x;
  if (i < n) o[i] = (_Float16)v[i];
}

// ---------------- rbfh GEMM: one wave per 64 edges (4 tiles of 16, eord order) ----------------
__global__ __launch_bounds__(64) void k_gemm_rbfh(
    const float* __restrict__ erbf, const _Float16* __restrict__ wf,
    const float* __restrict__ bsc, const int* __restrict__ eord,
    _Float16* __restrict__ rbfh)
{
  int lane = threadIdx.x;
  int i0 = blockIdx.x * 64;
  int ml = lane & 15, kg = lane >> 4;
  half8 a0[4], a1[4];
  #pragma unroll
  for (int tt = 0; tt < 4; tt++){
    int e_m = eord[i0 + tt*16 + ml];
    const float* ar = erbf + (size_t)e_m*64 + 8*kg;
    float4 p0 = *(const float4*)(ar);
    float4 p1 = *(const float4*)(ar+4);
    a0[tt][0]=(_Float16)p0.x; a0[tt][1]=(_Float16)p0.y; a0[tt][2]=(_Float16)p0.z; a0[tt][3]=(_Float16)p0.w;
    a0[tt][4]=(_Float16)p1.x; a0[tt][5]=(_Float16)p1.y; a0[tt][6]=(_Float16)p1.z; a0[tt][7]=(_Float16)p1.w;
    float4 p2 = *(const float4*)(ar+32);
    float4 p3 = *(const float4*)(ar+36);
    a1[tt][0]=(_Float16)p2.x; a1[tt][1]=(_Float16)p2.y; a1[tt][2]=(_Float16)p2.z; a1[tt][3]=(_Float16)p2.w;
    a1[tt][4]=(_Float16)p3.x; a1[tt][5]=(_Float16)p3.y; a1[tt][6]=(_Float16)p3.z; a1[tt][7]=(_Float16)p3.w;
  }
  #pragma unroll 2
  for (int nb = 0; nb < 24; nb++){
    half8 b0 = *(const half8*)(wf + ((size_t)(nb*2+0)*64 + lane)*8);
    half8 b1 = *(const half8*)(wf + ((size_t)(nb*2+1)*64 + lane)*8);
    float bias = bsc[nb*16 + ml];
    #pragma unroll
    for (int tt = 0; tt < 4; tt++){
      f32x4 acc = {bias, bias, bias, bias};
      acc = __builtin_amdgcn_mfma_f32_16x16x32_f16(a0[tt], b0, acc, 0, 0, 0);
      acc = __builtin_amdgcn_mfma_f32_16x16x32_f16(a1[tt], b1, acc, 0, 0, 0);
      _Float16* orow = rbfh + (size_t)(i0 + tt*16)*384 + nb*16 + ml;
      #pragma unroll
      for (int r = 0; r < 4; r++)
        orow[(size_t)(kg*4 + r)*384] = (_Float16)acc[r];
    }
  }
}

// ---------------- xh = ssilu(lnorm(x)@xp1+b)@xp2+b  (MFMA, 32 nodes/block) ----------------
__global__ __launch_bounds__(256) void k_xh_mfma(
    const float* __restrict__ x,
    const float* __restrict__ lnw, const float* __restrict__ lnb,
    const _Float16* __restrict__ wf1, const float* __restrict__ b1,
    const _Float16* __restrict__ wf2, const float* __restrict__ b2,
    _Float16* __restrict__ xh16)
{
  __shared__ _Float16 sA[32][136];
  __shared__ _Float16 sH[32][136];
  int t = threadIdx.x;
  int n0 = blockIdx.x * 32;
  // lnorm -> sA (f16)
  {
    int nd = t >> 3, sb = t & 7;
    int node = n0 + nd;
    float v[16];
    float s = 0.f, ss = 0.f;
    if (node < NN){
      const float* xr = x + (size_t)node*128 + sb*16;
      #pragma unroll
      for (int g = 0; g < 4; g++){
        float4 q = *(const float4*)(xr + g*4);
        v[g*4+0]=q.x; v[g*4+1]=q.y; v[g*4+2]=q.z; v[g*4+3]=q.w;
      }
      #pragma unroll
      for (int u = 0; u < 16; u++){ s += v[u]; ss += v[u]*v[u]; }
    } else {
      #pragma unroll
      for (int u = 0; u < 16; u++) v[u] = 0.f;
    }
    #pragma unroll
    for (int o2 = 4; o2 > 0; o2 >>= 1){
      s  += __shfl_xor(s, o2, 8);
      ss += __shfl_xor(ss, o2, 8);
    }
    float mean = s * (1.0f/128.0f);
    float var  = ss * (1.0f/128.0f) - mean*mean;
    float rstd = rsqrtf(var + 1e-5f);
    #pragma unroll
    for (int u = 0; u < 16; u++){
      int h = sb*16 + u;
      sA[nd][h] = (node < NN) ? (_Float16)((v[u]-mean)*rstd*lnw[h] + lnb[h]) : (_Float16)0.f;
    }
  }
  __syncthreads();
  int lane = t & 63, w = t >> 6, ml = lane & 15, kg = lane >> 4;
  int mt = w >> 1;
  // GEMM1: K=128 NO=128
  {
    half8 a[4];
    #pragma unroll
    for (int ks = 0; ks < 4; ks++)
      a[ks] = *(const half8*)&sA[mt*16 + ml][ks*32 + kg*8];
    float hout[4][4];
    #pragma unroll
    for (int nb4 = 0; nb4 < 4; nb4++){
      int nb = (w&1)*4 + nb4;
      float bias = b1[nb*16 + ml];
      f32x4 acc = {bias, bias, bias, bias};
      #pragma unroll
      for (int ks = 0; ks < 4; ks++)
        acc = __builtin_amdgcn_mfma_f32_16x16x32_f16(a[ks],
                *(const half8*)(wf1 + ((size_t)(nb*4+ks)*64 + lane)*8), acc, 0,0,0);
      #pragma unroll
      for (int r = 0; r < 4; r++) hout[nb4][r] = ssilu_f(acc[r]);
    }
    #pragma unroll
    for (int nb4 = 0; nb4 < 4; nb4++){
      int nb = (w&1)*4 + nb4;
      #pragma unroll
      for (int r = 0; r < 4; r++)
        sH[mt*16 + kg*4 + r][nb*16 + ml] = (_Float16)hout[nb4][r];
    }
  }
  __syncthreads();
  // GEMM2: K=128 NO=384 -> xh16
  {
    half8 a[4];
    #pragma unroll
    for (int ks = 0; ks < 4; ks++)
      a[ks] = *(const half8*)&sH[mt*16 + ml][ks*32 + kg*8];
    #pragma unroll 4
    for (int nb12 = 0; nb12 < 12; nb12++){
      int nb = (w&1)*12 + nb12;
      float bias = b2[nb*16 + ml];
      f32x4 acc = {bias, bias, bias, bias};
      #pragma unroll
      for (int ks = 0; ks < 4; ks++)
        acc = __builtin_amdgcn_mfma_f32_16x16x32_f16(a[ks],
                *(const half8*)(wf2 + ((size_t)(nb*4+ks)*64 + lane)*8), acc, 0,0,0);
      #pragma unroll
      for (int r = 0; r < 4; r++){
        int m = mt*16 + kg*4 + r;
        int node = n0 + m;
        if (node < NN) xh16[(size_t)node*384 + nb*16 + ml] = (_Float16)acc[r];
      }
    }
  }
}

// ---------------- edge kernel, f16 gathers ----------------
__global__ __launch_bounds__(256) void k_edge3(
    const _Float16* __restrict__ rbfh,
    const int* __restrict__ esrc,
    const int* __restrict__ eord, const int* __restrict__ off,
    const float* __restrict__ evec,
    const _Float16* __restrict__ xh16, const _Float16* __restrict__ vec16,
    float* __restrict__ dx, float* __restrict__ dvec)
{
  int t = threadIdx.x;
  int lane = t & 63;
  int n = blockIdx.x*4 + (t>>6);
  if (n >= NN) return;
  int o0 = off[n], o1 = off[n+1];
  float ax0 = 0.f, ax1 = 0.f;
  float av00=0.f, av01=0.f, av10=0.f, av11=0.f, av20=0.f, av21=0.f;
  #pragma unroll 2
  for (int p = o0; p < o1; p++){
    int eid = eord[p];
    const _Float16* hr = rbfh + (size_t)p*384;
    float h0 = (float)hr[lane];
    float h1 = (float)hr[64+lane];
    float h2 = (float)hr[128+lane];
    float h3 = (float)hr[192+lane];
    float h4 = (float)hr[256+lane];
    float h5 = (float)hr[320+lane];
    int sN = esrc[eid];
    const _Float16* xr = xh16 + (size_t)sN*384;
    float m0  = h0 * (float)xr[lane];
    float m1  = h1 * (float)xr[64+lane];
    float m2a = h2 * (float)xr[128+lane];
    float m2b = h3 * (float)xr[192+lane];
    float m3a = h4 * (float)xr[256+lane];
    float m3b = h5 * (float)xr[320+lane];
    ax0 += m0; ax1 += m1;
    const _Float16* vr = vec16 + (size_t)sN*384;
    float ev0 = evec[(size_t)eid*3 + 0];
    float ev1 = evec[(size_t)eid*3 + 1];
    float ev2 = evec[(size_t)eid*3 + 2];
    av00 = fmaf((float)vr[lane],     m2a, av00); av00 = fmaf(m3a, ev0, av00);
    av01 = fmaf((float)vr[64+lane],  m2b, av01); av01 = fmaf(m3b, ev0, av01);
    av10 = fmaf((float)vr[128+lane], m2a, av10); av10 = fmaf(m3a, ev1, av10);
    av11 = fmaf((float)vr[192+lane], m2b, av11); av11 = fmaf(m3b, ev1, av11);
    av20 = fmaf((float)vr[256+lane], m2a, av20); av20 = fmaf(m3a, ev2, av20);
    av21 = fmaf((float)vr[320+lane], m2b, av21); av21 = fmaf(m3b, ev2, av21);
  }
  float* dxr = dx + (size_t)n*128;
  dxr[lane] = ax0; dxr[64+lane] = ax1;
  float* dvr = dvec + (size_t)n*384;
  dvr[lane]     = av00 * INV_SQRT_Hf;
  dvr[64+lane]  = av01 * INV_SQRT_Hf;
  dvr[128+lane] = av10 * INV_SQRT_Hf;
  dvr[192+lane] = av11 * INV_SQRT_Hf;
  dvr[256+lane] = av20 * INV_SQRT_Hf;
  dvr[320+lane] = av21 * INV_SQRT_Hf;
}

// ---------------- node update (MFMA, 32 nodes/block) ----------------
__global__ __launch_bounds__(256) void k_node_mfma(
    float* __restrict__ xbuf, float* __restrict__ vbuf,
    const float* __restrict__ dx, const float* __restrict__ dvec,
    const _Float16* __restrict__ wfvp,
    const _Float16* __restrict__ wfxv1, const float* __restrict__ xv1_b,
    const _Float16* __restrict__ wfxv2, const float* __restrict__ xv2_b,
    _Float16* __restrict__ vec16)
{
  __shared__ _Float16 sV1[96][136];    // 26112 B
  __shared__ _Float16 sCat[32][264];   // 16896 B
  __shared__ _Float16 sVD[32][128];    //  8192 B
  int t = threadIdx.x;
  int n0 = blockIdx.x * 32;
  int lane = t & 63, w = t >> 6, ml = lane & 15, kg = lane >> 4;
  int mt = w & 1, nbb = (w >> 1) * 4;
  // Phase A: vp GEMM per component; v1/v2 paired in-wave
  float vd[4][4], vn[4][4];
  #pragma unroll
  for (int i=0;i<4;i++){
    #pragma unroll
    for (int r=0;r<4;r++){ vd[i][r]=0.f; vn[i][r]=0.f; }
  }
  int arow = n0 + mt*16 + ml;
  bool aok = arow < NN;
  for (int cd = 0; cd < 3; cd++){
    half8 a[4];
    #pragma unroll
    for (int ks = 0; ks < 4; ks++){
      if (aok){
        const float* vr = vbuf + (size_t)arow*384 + cd*128 + ks*32 + kg*8;
        const float* dr = dvec + (size_t)arow*384 + cd*128 + ks*32 + kg*8;
        float4 q0 = *(const float4*)(vr);
        float4 q1 = *(const float4*)(vr+4);
        float4 d0 = *(const float4*)(dr);
        float4 d1 = *(const float4*)(dr+4);
        a[ks][0]=(_Float16)(q0.x+d0.x); a[ks][1]=(_Float16)(q0.y+d0.y);
        a[ks][2]=(_Float16)(q0.z+d0.z); a[ks][3]=(_Float16)(q0.w+d0.w);
        a[ks][4]=(_Float16)(q1.x+d1.x); a[ks][5]=(_Float16)(q1.y+d1.y);
        a[ks][6]=(_Float16)(q1.z+d1.z); a[ks][7]=(_Float16)(q1.w+d1.w);
      } else {
        #pragma unroll
        for (int j=0;j<8;j++) a[ks][j] = (_Float16)0.f;
      }
    }
    #pragma unroll
    for (int nb4 = 0; nb4 < 4; nb4++){
      int nb1 = nbb + nb4;
      f32x4 acc1 = {0.f,0.f,0.f,0.f}, acc2 = {0.f,0.f,0.f,0.f};
      #pragma unroll
      for (int ks = 0; ks < 4; ks++){
        acc1 = __builtin_amdgcn_mfma_f32_16x16x32_f16(a[ks],
                 *(const half8*)(wfvp + ((size_t)(nb1*4+ks)*64 + lane)*8), acc1, 0,0,0);
        acc2 = __builtin_amdgcn_mfma_f32_16x16x32_f16(a[ks],
                 *(const half8*)(wfvp + ((size_t)((nb1+8)*4+ks)*64 + lane)*8), acc2, 0,0,0);
      }
      #pragma unroll
      for (int r = 0; r < 4; r++){
        float v1v = acc1[r], v2v = acc2[r];
        vd[nb4][r] += v1v*v2v;
        vn[nb4][r] += v2v*v2v;
        sV1[cd*32 + mt*16 + kg*4 + r][nb1*16 + ml] = (_Float16)v1v;
      }
    }
  }
  #pragma unroll
  for (int nb4 = 0; nb4 < 4; nb4++){
    #pragma unroll
    for (int r = 0; r < 4; r++){
      int m = mt*16 + kg*4 + r, c = (nbb+nb4)*16 + ml;
      sVD[m][c] = (_Float16)(vd[nb4][r] * INV_SQRT_Hf);
      sCat[m][128 + c] = (_Float16)sqrtf(vn[nb4][r] + 1e-8f);
    }
  }
  // Phase B: xn staging
  {
    int nd = t >> 3, sb = t & 7;
    int node = n0 + nd;
    if (node < NN){
      const float* xr = xbuf + (size_t)node*128 + sb*16;
      const float* dr = dx   + (size_t)node*128 + sb*16;
      #pragma unroll
      for (int g = 0; g < 4; g++){
        float4 qa = *(const float4*)(xr + g*4);
        float4 qb = *(const float4*)(dr + g*4);
        sCat[nd][sb*16+g*4+0] = (_Float16)((qa.x+qb.x)*INV_SQRT_2f);
        sCat[nd][sb*16+g*4+1] = (_Float16)((qa.y+qb.y)*INV_SQRT_2f);
        sCat[nd][sb*16+g*4+2] = (_Float16)((qa.z+qb.z)*INV_SQRT_2f);
        sCat[nd][sb*16+g*4+3] = (_Float16)((qa.w+qb.w)*INV_SQRT_2f);
      }
    } else {
      #pragma unroll
      for (int u = 0; u < 16; u++) sCat[nd][sb*16+u] = (_Float16)0.f;
    }
  }
  __syncthreads();
  // Phase C: h1 = ssilu(cat @ xv1 + b), K=256 NO=128
  float hreg[4][4];
  {
    half8 a[8];
    #pragma unroll
    for (int ks = 0; ks < 8; ks++)
      a[ks] = *(const half8*)&sCat[mt*16 + ml][ks*32 + kg*8];
    #pragma unroll
    for (int nb4 = 0; nb4 < 4; nb4++){
      int nb = (w>>1)*4 + nb4;
      float bias = xv1_b[nb*16 + ml];
      f32x4 acc = {bias, bias, bias, bias};
      #pragma unroll
      for (int ks = 0; ks < 8; ks++)
        acc = __builtin_amdgcn_mfma_f32_16x16x32_f16(a[ks],
                *(const half8*)(wfxv1 + ((size_t)(nb*8+ks)*64 + lane)*8), acc, 0,0,0);
      #pragma unroll
      for (int r = 0; r < 4; r++) hreg[nb4][r] = ssilu_f(acc[r]);
    }
  }
  __syncthreads();
  #pragma unroll
  for (int nb4 = 0; nb4 < 4; nb4++){
    int nb = (w>>1)*4 + nb4;
    #pragma unroll
    for (int r = 0; r < 4; r++)
      sCat[mt*16 + kg*4 + r][nb*16 + ml] = (_Float16)hreg[nb4][r];
  }
  __syncthreads();
  // Phase D: g = h1 @ xv2 + b (K=128, NO=384) + final updates
  {
    half8 a[4];
    #pragma unroll
    for (int ks = 0; ks < 4; ks++)
      a[ks] = *(const half8*)&sCat[mt*16 + ml][ks*32 + kg*8];
    #pragma unroll 2
    for (int nb4 = 0; nb4 < 4; nb4++){
      int nbu = nbb + nb4;
      float b1v = xv2_b[nbu*16 + ml];
      float b2v = xv2_b[(nbu+8)*16 + ml];
      float b3v = xv2_b[(nbu+16)*16 + ml];
      f32x4 au1 = {b1v,b1v,b1v,b1v};
      f32x4 au2 = {b2v,b2v,b2v,b2v};
      f32x4 au3 = {b3v,b3v,b3v,b3v};
      #pragma unroll
      for (int ks = 0; ks < 4; ks++){
        au1 = __builtin_amdgcn_mfma_f32_16x16x32_f16(a[ks],
                *(const half8*)(wfxv2 + ((size_t)(nbu*4+ks)*64 + lane)*8), au1, 0,0,0);
        au2 = __builtin_amdgcn_mfma_f32_16x16x32_f16(a[ks],
                *(const half8*)(wfxv2 + ((size_t)((nbu+8)*4+ks)*64 + lane)*8), au2, 0,0,0);
        au3 = __builtin_amdgcn_mfma_f32_16x16x32_f16(a[ks],
                *(const half8*)(wfxv2 + ((size_t)((nbu+16)*4+ks)*64 + lane)*8), au3, 0,0,0);
      }
      #pragma unroll
      for (int r = 0; r < 4; r++){
        int m = mt*16 + kg*4 + r;
        int node = n0 + m;
        if (node >= NN) continue;
        int c = nbu*16 + ml;
        float xu1 = au1[r], xu2 = au2[r], xu3 = au3[r];
        float vdv = (float)sVD[m][c];
        size_t px = (size_t)node*128 + c;
        float xn = (xbuf[px] + dx[px]) * INV_SQRT_2f;
        xbuf[px] = xn + (xu1 + xu2*vdv) * INV_SQRT_2f;
        #pragma unroll
        for (int cd = 0; cd < 3; cd++){
          float v1v = (float)sV1[cd*32 + m][c];
          size_t pv = (size_t)node*384 + cd*128 + c;
          float vo = vbuf[pv] + dvec[pv] + xu3*v1v;
          vbuf[pv] = vo;
          vec16[pv] = (_Float16)vo;
        }
      }
    }
  }
}

// ---------------- final: energy + gated block 1 (8 nodes / block) ----------------
__global__ __launch_bounds__(256) void k_final1(
    const float* __restrict__ x, const float* __restrict__ vec,
    const float* __restrict__ we1, const float* __restrict__ be1,
    const float* __restrict__ we2, const float* __restrict__ be2,
    const float* __restrict__ wv1, const float* __restrict__ wv2,
    const float* __restrict__ wu1, const float* __restrict__ bu1,
    const float* __restrict__ wu2, const float* __restrict__ bu2,
    float* __restrict__ out, float* __restrict__ fx, float* __restrict__ fv)
{
  __shared__ __align__(16) float s_x[8][128];
  __shared__ __align__(16) float s_vl[8][384];
  __shared__ __align__(16) float s_p[8][384];
  __shared__ __align__(16) float s_n1[8][128];
  __shared__ __align__(16) float s_v2[8][192];
  __shared__ __align__(16) float s_h[8][128];
  __shared__ __align__(16) float s_h2[8][128];
  __shared__ __align__(16) float s_e1[8][64];
  int t = threadIdx.x;
  int n0 = blockIdx.x * 8;
  for (int idx = t; idx < 8*128; idx += 256){
    int i = idx >> 7, h = idx & 127;
    s_x[i][h] = x[(size_t)(n0+i)*128 + h];
  }
  for (int idx = t; idx < 8*384; idx += 256){
    int i = idx / 384, h = idx % 384;
    s_vl[i][h] = vec[(size_t)(n0+i)*384 + h];
  }
  __syncthreads();
  {
    int c = t & 63;
    int gb = t >> 6;
    #pragma unroll
    for (int u = 0; u < 2; u++){
      int i = gb + 4*u;
      float acc = be1[c];
      for (int k = 0; k < 128; k += 4){
        float w0 = we1[(k+0)*64+c], wq = we1[(k+1)*64+c], wz = we1[(k+2)*64+c], ww = we1[(k+3)*64+c];
        float4 a = *(const float4*)&s_x[i][k];
        acc = fmaf(a.x,w0,acc); acc=fmaf(a.y,wq,acc); acc=fmaf(a.z,wz,acc); acc=fmaf(a.w,ww,acc);
      }
      s_e1[i][c] = ssilu_f(acc);
    }
  }
  __syncthreads();
  {
    int lane = t & 63;
    int gb = t >> 6;
    #pragma unroll
    for (int u = 0; u < 2; u++){
      int i = gb + 4*u;
      float v = s_e1[i][lane] * we2[lane];
      #pragma unroll
      for (int off = 32; off > 0; off >>= 1) v += __shfl_xor(v, off, 64);
      if (lane == 0) out[(size_t)(n0+i)*4 + 0] = v + be2[0];
    }
  }
  {
    int ob = t & 127;
    int ib = (t >> 7) * 4;
    float acc[4][3];
    #pragma unroll
    for (int ii=0;ii<4;ii++){
      #pragma unroll
      for (int cd=0;cd<3;cd++) acc[ii][cd]=0.f;
    }
    for (int k = 0; k < 128; k += 4){
      float w0 = wv1[(k+0)*128+ob], wq=wv1[(k+1)*128+ob], wz=wv1[(k+2)*128+ob], ww=wv1[(k+3)*128+ob];
      #pragma unroll
      for (int ii=0;ii<4;ii++){
        #pragma unroll
        for (int cd=0;cd<3;cd++){
          float4 a = *(const float4*)&s_vl[ib+ii][cd*128+k];
          float s0=acc[ii][cd];
          s0=fmaf(a.x,w0,s0); s0=fmaf(a.y,wq,s0); s0=fmaf(a.z,wz,s0); s0=fmaf(a.w,ww,s0);
          acc[ii][cd]=s0;
        }
      }
    }
    #pragma unroll
    for (int ii=0;ii<4;ii++){
      #pragma unroll
      for (int cd=0;cd<3;cd++) s_p[ib+ii][cd*128+ob] = acc[ii][cd];
    }
  }
  __syncthreads();
  #pragma unroll
  for (int rep = 0; rep < 4; rep++){
    int idx = rep*256+t;
    int i = idx >> 7, h = idx & 127;
    float p0 = s_p[i][h], p1 = s_p[i][128+h], p2 = s_p[i][256+h];
    s_n1[i][h] = sqrtf(p0*p0 + p1*p1 + p2*p2);
  }
  {
    int c = t & 63;
    int gb = t >> 6;
    float acc[2][3];
    #pragma unroll
    for (int u=0;u<2;u++){
      #pragma unroll
      for (int cd=0;cd<3;cd++) acc[u][cd]=0.f;
    }
    for (int k=0;k<128;k+=4){
      float w0=wv2[(k+0)*64+c], wq=wv2[(k+1)*64+c], wz=wv2[(k+2)*64+c], ww=wv2[(k+3)*64+c];
      #pragma unroll
      for (int u=0;u<2;u++){
        int i = gb + 4*u;
        #pragma unroll
        for (int cd=0;cd<3;cd++){
          float4 a = *(const float4*)&s_vl[i][cd*128+k];
          float s0=acc[u][cd];
          s0=fmaf(a.x,w0,s0); s0=fmaf(a.y,wq,s0); s0=fmaf(a.z,wz,s0); s0=fmaf(a.w,ww,s0);
          acc[u][cd]=s0;
        }
      }
    }
    #pragma unroll
    for (int u=0;u<2;u++){
      int i=gb+4*u;
      #pragma unroll
      for (int cd=0;cd<3;cd++) s_v2[i][cd*64+c]=acc[u][cd];
    }
  }
  __syncthreads();
  {
    int c = t & 127;
    int ib = (t >> 7) * 4;
    float acc[4];
    float bv = bu1[c];
    #pragma unroll
    for (int ii=0;ii<4;ii++) acc[ii]=bv;
    for (int k=0;k<128;k+=4){
      float w0=wu1[(k+0)*128+c], wq=wu1[(k+1)*128+c], wz=wu1[(k+2)*128+c], ww=wu1[(k+3)*128+c];
      #pragma unroll
      for (int ii=0;ii<4;ii++){
        float4 a = *(const float4*)&s_x[ib+ii][k];
        acc[ii]=fmaf(a.x,w0,acc[ii]); acc[ii]=fmaf(a.y,wq,acc[ii]); acc[ii]=fmaf(a.z,wz,acc[ii]); acc[ii]=fmaf(a.w,ww,acc[ii]);
      }
    }
    for (int k=0;k<128;k+=4){
      float w0=wu1[(128+k+0)*128+c], wq=wu1[(128+k+1)*128+c], wz=wu1[(128+k+2)*128+c], ww=wu1[(128+k+3)*128+c];
      #pragma unroll
      for (int ii=0;ii<4;ii++){
        float4 a = *(const float4*)&s_n1[ib+ii][k];
        acc[ii]=fmaf(a.x,w0,acc[ii]); acc[ii]=fmaf(a.y,wq,acc[ii]); acc[ii]=fmaf(a.z,wz,acc[ii]); acc[ii]=fmaf(a.w,ww,acc[ii]);
      }
    }
    #pragma unroll
    for (int ii=0;ii<4;ii++) s_h[ib+ii][c] = ssilu_f(acc[ii]);
  }
  __syncthreads();
  {
    int c = t & 127;
    int ib = (t >> 7) * 4;
    float acc[4];
    float bv = bu2[c];
    #pragma unroll
    for (int ii=0;ii<4;ii++) acc[ii]=bv;
    for (int k=0;k<128;k+=4){
      float w0=wu2[(k+0)*128+c], wq=wu2[(k+1)*128+c], wz=wu2[(k+2)*128+c], ww=wu2[(k+3)*128+c];
      #pragma unroll
      for (int ii=0;ii<4;ii++){
        float4 a = *(const float4*)&s_h[ib+ii][k];
        acc[ii]=fmaf(a.x,w0,acc[ii]); acc[ii]=fmaf(a.y,wq,acc[ii]); acc[ii]=fmaf(a.z,wz,acc[ii]); acc[ii]=fmaf(a.w,ww,acc[ii]);
      }
    }
    #pragma unroll
    for (int ii=0;ii<4;ii++) s_h2[ib+ii][c] = acc[ii];
  }
  __syncthreads();
  {
    int c = t & 63;
    int gb = t >> 6;
    #pragma unroll
    for (int u=0;u<2;u++){
      int i = gb + 4*u;
      fx[(size_t)(n0+i)*64 + c] = ssilu_f(s_h2[i][c]);
      float xv = s_h2[i][64+c];
      #pragma unroll
      for (int cd=0;cd<3;cd++)
        fv[(size_t)(n0+i)*192 + cd*64 + c] = xv * s_v2[i][cd*64+c];
    }
  }
}

// ---------------- final: gated block 2 -> forces ----------------
__global__ __launch_bounds__(256) void k_final2(
    const float* __restrict__ fx, const float* __restrict__ fv,
    const float* __restrict__ wv1, const float* __restrict__ wv2,
    const float* __restrict__ wu1, const float* __restrict__ bu1,
    const float* __restrict__ wu2, const float* __restrict__ bu2,
    float* __restrict__ out)
{
  int t = threadIdx.x;
  int lane = t & 63;
  int n = blockIdx.x * 4 + (t >> 6);
  float fxv = fx[(size_t)n*64 + lane];
  float f0 = fv[(size_t)n*192 + lane];
  float f1 = fv[(size_t)n*192 + 64 + lane];
  float f2 = fv[(size_t)n*192 + 128 + lane];
  float a0=0.f, a1=0.f, a2=0.f;
  for (int k=0;k<64;k++){
    float w = wv1[k*64 + lane];
    a0 = fmaf(bcast(f0,k), w, a0);
    a1 = fmaf(bcast(f1,k), w, a1);
    a2 = fmaf(bcast(f2,k), w, a2);
  }
  float n1 = sqrtf(a0*a0 + a1*a1 + a2*a2);
  float w2v = wv2[lane];
  float r0 = f0*w2v, r1 = f1*w2v, r2 = f2*w2v;
  #pragma unroll
  for (int off=32; off>0; off>>=1){
    r0 += __shfl_xor(r0, off, 64);
    r1 += __shfl_xor(r1, off, 64);
    r2 += __shfl_xor(r2, off, 64);
  }
  float acc = bu1[lane];
  for (int k=0;k<64;k++) acc = fmaf(bcast(fxv,k), wu1[k*64+lane], acc);
  for (int k=0;k<64;k++) acc = fmaf(bcast(n1,k), wu1[(64+k)*64+lane], acc);
  float hv = ssilu_f(acc);
  float s1 = hv * wu2[lane*2 + 1];
  #pragma unroll
  for (int off=32; off>0; off>>=1) s1 += __shfl_xor(s1, off, 64);
  float h2_1 = s1 + bu2[1];
  if (lane == 0){
    out[(size_t)n*4 + 1] = h2_1 * r0;
    out[(size_t)n*4 + 2] = h2_1 * r1;
    out[(size_t)n*4 + 3] = h2_1 * r2;
  }
}

extern "C" void kernel_launch(void* const* d_in, const int* in_sizes, int n_in,
                              void* d_out, int out_size, void* d_ws, size_t ws_size,
                              hipStream_t stream)
{
  const float* x_in   = (const float*)d_in[0];
  const float* vec_in = (const float*)d_in[1];
  const int*   eidx   = (const int*)d_in[2];
  const float* erbf   = (const float*)d_in[3];
  const float* evec   = (const float*)d_in[4];
  const float* ln_w  = (const float*)d_in[5];
  const float* ln_b  = (const float*)d_in[6];
  const float* xp1_w = (const float*)d_in[7];
  const float* xp1_b = (const float*)d_in[8];
  const float* xp2_w = (const float*)d_in[9];
  const float* xp2_b = (const float*)d_in[10];
  const float* rbf_w = (const float*)d_in[11];
  const float* rbf_b = (const float*)d_in[12];
  const float* vp_w  = (const float*)d_in[13];
  const float* xv1_w = (const float*)d_in[14];
  const float* xv1_b = (const float*)d_in[15];
  const float* xv2_w = (const float*)d_in[16];
  const float* xv2_b = (const float*)d_in[17];
  const float* we1 = (const float*)d_in[18];
  const float* be1 = (const float*)d_in[19];
  const float* we2 = (const float*)d_in[20];
  const float* be2 = (const float*)d_in[21];
  const float* g1_v1 = (const float*)d_in[22];
  const float* g1_v2 = (const float*)d_in[23];
  const float* g1_u1 = (const float*)d_in[24];
  const float* g1_u1b = (const float*)d_in[25];
  const float* g1_u2 = (const float*)d_in[26];
  const float* g1_u2b = (const float*)d_in[27];
  const float* g2_v1 = (const float*)d_in[28];
  const float* g2_v2 = (const float*)d_in[29];
  const float* g2_u1 = (const float*)d_in[30];
  const float* g2_u1b = (const float*)d_in[31];
  const float* g2_u2 = (const float*)d_in[32];
  const float* g2_u2b = (const float*)d_in[33];
  float* out = (float*)d_out;

  char* base = (char*)d_ws;
  size_t o = 0;
  auto alloc = [&](size_t bytes) -> char* {
    char* p = base + o;
    o = (o + bytes + 255) & ~(size_t)255;
    return p;
  };
  float* x_cur   = (float*)alloc((size_t)NN*128*4);
  float* vec_cur = (float*)alloc((size_t)NN*384*4);
  float* dx      = (float*)alloc((size_t)NN*128*4);
  float* dvec    = (float*)alloc((size_t)NN*384*4);
  _Float16* xh16 = (_Float16*)alloc((size_t)NN*384*2);
  _Float16* vec16= (_Float16*)alloc((size_t)NN*384*2);
  int*   eord    = (int*)alloc((size_t)EE*4);
  int*   off     = (int*)alloc((size_t)(NN+1)*4);
  _Float16* wf   = (_Float16*)alloc((size_t)LL*24576*2);
  float* bsc     = (float*)alloc((size_t)LL*384*4);
  _Float16* wfn  = (_Float16*)alloc((size_t)LL*180224*2);
  _Float16* rbfh = (_Float16*)alloc((size_t)EE*384*2);
  float* fxb = dx;      // N*64  (dx free during finals)
  float* fvb = dvec;    // N*192 (dvec free during finals)
  int* cnt = (int*)dx;  // pre-layer-0 reuse
  int* cur = cnt + NN;

  hipMemcpyAsync(x_cur, x_in, sizeof(float)*(size_t)NN*128, hipMemcpyDeviceToDevice, stream);
  hipMemcpyAsync(vec_cur, vec_in, sizeof(float)*(size_t)NN*384, hipMemcpyDeviceToDevice, stream);

  const int* esrc = eidx;
  const int* edst = eidx + EE;

  hipMemsetAsync(cnt, 0, sizeof(int)*NN, stream);
  k_hist<<<(EE+255)/256, 256, 0, stream>>>(edst, cnt);
  k_scan<<<1, 1024, 0, stream>>>(cnt, off, cur);
  k_fill<<<(EE+255)/256, 256, 0, stream>>>(edst, cur, eord);
  k_packw<<<(LL*24576+255)/256, 256, 0, stream>>>(rbf_w, wf);
  k_packb<<<(LL*384+255)/256, 256, 0, stream>>>(rbf_b, bsc);
  k_cvt16<<<(NN*384+255)/256, 256, 0, stream>>>(vec_in, vec16, NN*384);

  // pack node weights: per layer offsets in wfn
  {
    PackTab tb;
    for (int l = 0; l < LL; l++){
      _Float16* wb = wfn + (size_t)l*180224;
      tb.s[l*5+0] = xp1_w + (size_t)l*128*128; tb.d[l*5+0] = wb;          tb.K[l*5+0]=128; tb.NO[l*5+0]=128;
      tb.s[l*5+1] = xp2_w + (size_t)l*128*384; tb.d[l*5+1] = wb+16384;    tb.K[l*5+1]=128; tb.NO[l*5+1]=384;
      tb.s[l*5+2] = vp_w  + (size_t)l*128*256; tb.d[l*5+2] = wb+65536;    tb.K[l*5+2]=128; tb.NO[l*5+2]=256;
      tb.s[l*5+3] = xv1_w + (size_t)l*256*128; tb.d[l*5+3] = wb+98304;    tb.K[l*5+3]=256; tb.NO[l*5+3]=128;
      tb.s[l*5+4] = xv2_w + (size_t)l*128*384; tb.d[l*5+4] = wb+131072;   tb.K[l*5+4]=128; tb.NO[l*5+4]=384;
    }
    k_packall<<<dim3(24, 30), 256, 0, stream>>>(tb);
  }

  for (int l = 0; l < LL; l++){
    _Float16* wb = wfn + (size_t)l*180224;
    k_xh_mfma<<<(NN+31)/32, 256, 0, stream>>>(x_cur, ln_w + l*128, ln_b + l*128,
        wb, xp1_b + l*128, wb+16384, xp2_b + l*384, xh16);
    k_gemm_rbfh<<<EE/64, 64, 0, stream>>>(erbf, wf + (size_t)l*24576,
        bsc + (size_t)l*384, eord, rbfh);
    k_edge3<<<NN/4, 256, 0, stream>>>(rbfh, esrc, eord, off, evec, xh16, vec16, dx, dvec);
    k_node_mfma<<<(NN+31)/32, 256, 0, stream>>>(x_cur, vec_cur, dx, dvec,
        wb+65536, wb+98304, xv1_b + l*128, wb+131072, xv2_b + l*384, vec16);
  }
  k_final1<<<NN/8, 256, 0, stream>>>(x_cur, vec_cur, we1, be1, we2, be2,
      g1_v1, g1_v2, g1_u1, g1_u1b, g1_u2, g1_u2b, out, fxb, fvb);
  k_final2<<<NN/4, 256, 0, stream>>>(fxb, fvb, g2_v1, g2_v2, g2_u1, g2_u1b, g2_u2, g2_u2b, out);
}

// Round 5
// 972.650 us; speedup vs baseline: 2.7925x; 1.1157x over previous
//
#include <hip/hip_runtime.h>
#include <hip/hip_bf16.h>

#define NN 10000
#define EE 160000
#define LL 6

#define INV_SQRT_3f  0.57735026919f
#define INV_SQRT_Hf  0.08838834764832f
#define INV_SQRT_2f  0.70710678118655f

typedef _Float16 half8 __attribute__((ext_vector_type(8)));
typedef float f32x4 __attribute__((ext_vector_type(4)));

// offsets (in f16 elements) into the packed final-weight buffer
#define WE1OFF   0
#define WV1OFF   8192
#define WV2OFF   24576
#define WU1OFF   32768
#define WU2OFF   65536
#define G2V1OFF  81920
#define G2U1OFF  86016
#define WFIN_SZ  94208

__device__ __forceinline__ float ssilu_f(float v){
  float s = 1.0f / (1.0f + __expf(-v));
  return v * s * 1.6666666666667f;
}
__device__ __forceinline__ float bcast(float v, int l){
  return __int_as_float(__builtin_amdgcn_readlane(__float_as_int(v), l));
}

// ---------------- CSR build ----------------
__global__ __launch_bounds__(256) void k_hist(const int* __restrict__ edst, int* __restrict__ cnt){
  int i = blockIdx.x*256 + threadIdx.x;
  if (i < EE) atomicAdd(&cnt[edst[i]], 1);
}

__global__ __launch_bounds__(1024) void k_scan(const int* __restrict__ cnt,
                                               int* __restrict__ off, int* __restrict__ cur){
  __shared__ int ps[1024];
  int t = threadIdx.x;
  int base = t*10;
  int local[10];
  int s = 0;
  #pragma unroll
  for (int i=0;i<10;i++){
    int c = (base+i < NN) ? cnt[base+i] : 0;
    local[i] = s; s += c;
  }
  ps[t] = s;
  __syncthreads();
  for (int d=1; d<1024; d<<=1){
    int v = (t>=d) ? ps[t-d] : 0;
    __syncthreads();
    ps[t] += v;
    __syncthreads();
  }
  int pre = (t>0) ? ps[t-1] : 0;
  #pragma unroll
  for (int i=0;i<10;i++){
    int idx = base+i;
    if (idx < NN){ int o = pre + local[i]; off[idx]=o; cur[idx]=o; }
  }
  if (t==1023) off[NN] = ps[1023];
}

__global__ __launch_bounds__(256) void k_fill(const int* __restrict__ edst,
                                              int* __restrict__ cur, int* __restrict__ eord){
  int i = blockIdx.x*256 + threadIdx.x;
  if (i < EE){
    int d = edst[i];
    int p = atomicAdd(&cur[d], 1);
    eord[p] = i;
  }
}

// ---------------- edge pre-sort (once; eord is layer-invariant) ----------------
// eA[((tile*2+kh)*64+lane)*8+j] = erbf[eord[tile*16+(lane&15)]*64 + kh*32 + (lane>>4)*8 + j]
__global__ __launch_bounds__(256) void k_sorta(const float* __restrict__ erbf,
                                               const int* __restrict__ eord, _Float16* __restrict__ eA){
  long i = (long)blockIdx.x*256 + threadIdx.x;
  if (i >= (long)EE*64) return;
  int j = i & 7, lane = (i >> 3) & 63, kh = (i >> 9) & 1;
  long tile = i >> 10;
  int e = eord[tile*16 + (lane&15)];
  eA[i] = (_Float16)erbf[(size_t)e*64 + kh*32 + (lane>>4)*8 + j];
}

__global__ __launch_bounds__(256) void k_sorte(const int* __restrict__ esrc, const float* __restrict__ evec,
                                               const int* __restrict__ eord, float4* __restrict__ es4){
  int p = blockIdx.x*256 + threadIdx.x;
  if (p >= EE) return;
  int e = eord[p];
  es4[p] = make_float4(evec[(size_t)e*3], evec[(size_t)e*3+1], evec[(size_t)e*3+2],
                       __int_as_float(esrc[e]));
}

// ---------------- pack rbf_w into f16 MFMA B-fragment layout (+ INV_SQRT_3 fold) ----------------
__global__ __launch_bounds__(256) void k_packw(const float* __restrict__ w, _Float16* __restrict__ wf){
  int i = blockIdx.x*256 + threadIdx.x;
  if (i >= LL*24*2*64*8) return;
  int j    = i & 7;
  int lane = (i >> 3) & 63;
  int kh   = (i >> 9) & 1;
  int rest = i >> 10;          // l*24 + nb
  int nb   = rest % 24;
  int l    = rest / 24;
  int k    = 32*kh + 8*(lane>>4) + j;
  int ch   = nb*16 + (lane&15);
  float v = w[((size_t)l*64 + k)*384 + ch];
  if (ch >= 128 && ch < 256) v *= INV_SQRT_3f;
  wf[i] = (_Float16)v;
}

__global__ __launch_bounds__(256) void k_packb(const float* __restrict__ b, float* __restrict__ bsc){
  int i = blockIdx.x*256 + threadIdx.x;
  if (i >= LL*384) return;
  int ch = i % 384;
  float v = b[i];
  if (ch >= 128 && ch < 256) v *= INV_SQRT_3f;
  bsc[i] = v;
}

// ---------------- generic pack: f32 [K][NO] -> f16 B-fragment order ----------------
struct PackTab {
  const float* s[40];
  _Float16* d[40];
  int K[40];
  int NO[40];
};
__global__ __launch_bounds__(256) void k_packall(PackTab tb){
  int e = blockIdx.y;
  int K = tb.K[e], NO = tb.NO[e];
  int tot = K*NO, KS = K >> 5;
  const float* s = tb.s[e];
  _Float16* d = tb.d[e];
  for (int i = blockIdx.x*256 + threadIdx.x; i < tot; i += gridDim.x*256){
    int j = i & 7, lane = (i >> 3) & 63, rest = i >> 9;
    int ks = rest % KS, nb = rest / KS;
    int k = ks*32 + (lane>>4)*8 + j, n = nb*16 + (lane&15);
    d[i] = (_Float16)s[(size_t)k*NO + n];
  }
}

__global__ __launch_bounds__(256) void k_cvt16(const float* __restrict__ v, _Float16* __restrict__ o, int n){
  int i = blockIdx.x*256 + threadIdx.x;
  if (i < n) o[i] = (_Float16)v[i];
}

// ---------------- rbfh GEMM: one wave per 64 edges (4 tiles of 16, eord order) ----------------
__global__ __launch_bounds__(64) void k_gemm_rbfh(
    const _Float16* __restrict__ eA, const _Float16* __restrict__ wf,
    const float* __restrict__ bsc,
    _Float16* __restrict__ rbfh)
{
  int lane = threadIdx.x;
  int i0 = blockIdx.x * 64;
  int tg = blockIdx.x * 4;
  int ml = lane & 15, kg = lane >> 4;
  half8 a0[4], a1[4];
  #pragma unroll
  for (int tt = 0; tt < 4; tt++){
    a0[tt] = *(const half8*)(eA + ((size_t)((tg+tt)*2+0)*64 + lane)*8);
    a1[tt] = *(const half8*)(eA + ((size_t)((tg+tt)*2+1)*64 + lane)*8);
  }
  #pragma unroll 2
  for (int nb = 0; nb < 24; nb++){
    half8 b0 = *(const half8*)(wf + ((size_t)(nb*2+0)*64 + lane)*8);
    half8 b1 = *(const half8*)(wf + ((size_t)(nb*2+1)*64 + lane)*8);
    float bias = bsc[nb*16 + ml];
    #pragma unroll
    for (int tt = 0; tt < 4; tt++){
      f32x4 acc = {bias, bias, bias, bias};
      acc = __builtin_amdgcn_mfma_f32_16x16x32_f16(a0[tt], b0, acc, 0, 0, 0);
      acc = __builtin_amdgcn_mfma_f32_16x16x32_f16(a1[tt], b1, acc, 0, 0, 0);
      _Float16* orow = rbfh + (size_t)(i0 + tt*16)*384 + nb*16 + ml;
      #pragma unroll
      for (int r = 0; r < 4; r++)
        orow[(size_t)(kg*4 + r)*384] = (_Float16)acc[r];
    }
  }
}

// ---------------- xh = ssilu(lnorm(x)@xp1+b)@xp2+b  (MFMA, 32 nodes/block) ----------------
__global__ __launch_bounds__(256) void k_xh_mfma(
    const float* __restrict__ x,
    const float* __restrict__ lnw, const float* __restrict__ lnb,
    const _Float16* __restrict__ wf1, const float* __restrict__ b1,
    const _Float16* __restrict__ wf2, const float* __restrict__ b2,
    _Float16* __restrict__ xh16)
{
  __shared__ _Float16 sA[32][136];
  __shared__ _Float16 sH[32][136];
  int t = threadIdx.x;
  int n0 = blockIdx.x * 32;
  {
    int nd = t >> 3, sb = t & 7;
    int node = n0 + nd;
    float v[16];
    float s = 0.f, ss = 0.f;
    if (node < NN){
      const float* xr = x + (size_t)node*128 + sb*16;
      #pragma unroll
      for (int g = 0; g < 4; g++){
        float4 q = *(const float4*)(xr + g*4);
        v[g*4+0]=q.x; v[g*4+1]=q.y; v[g*4+2]=q.z; v[g*4+3]=q.w;
      }
      #pragma unroll
      for (int u = 0; u < 16; u++){ s += v[u]; ss += v[u]*v[u]; }
    } else {
      #pragma unroll
      for (int u = 0; u < 16; u++) v[u] = 0.f;
    }
    #pragma unroll
    for (int o2 = 4; o2 > 0; o2 >>= 1){
      s  += __shfl_xor(s, o2, 8);
      ss += __shfl_xor(ss, o2, 8);
    }
    float mean = s * (1.0f/128.0f);
    float var  = ss * (1.0f/128.0f) - mean*mean;
    float rstd = rsqrtf(var + 1e-5f);
    #pragma unroll
    for (int u = 0; u < 16; u++){
      int h = sb*16 + u;
      sA[nd][h] = (node < NN) ? (_Float16)((v[u]-mean)*rstd*lnw[h] + lnb[h]) : (_Float16)0.f;
    }
  }
  __syncthreads();
  int lane = t & 63, w = t >> 6, ml = lane & 15, kg = lane >> 4;
  int mt = w >> 1;
  {
    half8 a[4];
    #pragma unroll
    for (int ks = 0; ks < 4; ks++)
      a[ks] = *(const half8*)&sA[mt*16 + ml][ks*32 + kg*8];
    float hout[4][4];
    #pragma unroll
    for (int nb4 = 0; nb4 < 4; nb4++){
      int nb = (w&1)*4 + nb4;
      float bias = b1[nb*16 + ml];
      f32x4 acc = {bias, bias, bias, bias};
      #pragma unroll
      for (int ks = 0; ks < 4; ks++)
        acc = __builtin_amdgcn_mfma_f32_16x16x32_f16(a[ks],
                *(const half8*)(wf1 + ((size_t)(nb*4+ks)*64 + lane)*8), acc, 0,0,0);
      #pragma unroll
      for (int r = 0; r < 4; r++) hout[nb4][r] = ssilu_f(acc[r]);
    }
    #pragma unroll
    for (int nb4 = 0; nb4 < 4; nb4++){
      int nb = (w&1)*4 + nb4;
      #pragma unroll
      for (int r = 0; r < 4; r++)
        sH[mt*16 + kg*4 + r][nb*16 + ml] = (_Float16)hout[nb4][r];
    }
  }
  __syncthreads();
  {
    half8 a[4];
    #pragma unroll
    for (int ks = 0; ks < 4; ks++)
      a[ks] = *(const half8*)&sH[mt*16 + ml][ks*32 + kg*8];
    #pragma unroll 4
    for (int nb12 = 0; nb12 < 12; nb12++){
      int nb = (w&1)*12 + nb12;
      float bias = b2[nb*16 + ml];
      f32x4 acc = {bias, bias, bias, bias};
      #pragma unroll
      for (int ks = 0; ks < 4; ks++)
        acc = __builtin_amdgcn_mfma_f32_16x16x32_f16(a[ks],
                *(const half8*)(wf2 + ((size_t)(nb*4+ks)*64 + lane)*8), acc, 0,0,0);
      #pragma unroll
      for (int r = 0; r < 4; r++){
        int m = mt*16 + kg*4 + r;
        int node = n0 + m;
        if (node < NN) xh16[(size_t)node*384 + nb*16 + ml] = (_Float16)acc[r];
      }
    }
  }
}

// ---------------- edge kernel, f16 gathers, pre-sorted edge constants ----------------
__global__ __launch_bounds__(256) void k_edge3(
    const _Float16* __restrict__ rbfh,
    const float4* __restrict__ es4, const int* __restrict__ off,
    const _Float16* __restrict__ xh16, const _Float16* __restrict__ vec16,
    float* __restrict__ dx, float* __restrict__ dvec)
{
  int t = threadIdx.x;
  int lane = t & 63;
  int n = blockIdx.x*4 + (t>>6);
  if (n >= NN) return;
  int o0 = off[n], o1 = off[n+1];
  float ax0 = 0.f, ax1 = 0.f;
  float av00=0.f, av01=0.f, av10=0.f, av11=0.f, av20=0.f, av21=0.f;
  #pragma unroll 2
  for (int p = o0; p < o1; p++){
    const _Float16* hr = rbfh + (size_t)p*384;
    float h0 = (float)hr[lane];
    float h1 = (float)hr[64+lane];
    float h2 = (float)hr[128+lane];
    float h3 = (float)hr[192+lane];
    float h4 = (float)hr[256+lane];
    float h5 = (float)hr[320+lane];
    float4 q = es4[p];
    int sN = __float_as_int(q.w);
    const _Float16* xr = xh16 + (size_t)sN*384;
    float m0  = h0 * (float)xr[lane];
    float m1  = h1 * (float)xr[64+lane];
    float m2a = h2 * (float)xr[128+lane];
    float m2b = h3 * (float)xr[192+lane];
    float m3a = h4 * (float)xr[256+lane];
    float m3b = h5 * (float)xr[320+lane];
    ax0 += m0; ax1 += m1;
    const _Float16* vr = vec16 + (size_t)sN*384;
    av00 = fmaf((float)vr[lane],     m2a, av00); av00 = fmaf(m3a, q.x, av00);
    av01 = fmaf((float)vr[64+lane],  m2b, av01); av01 = fmaf(m3b, q.x, av01);
    av10 = fmaf((float)vr[128+lane], m2a, av10); av10 = fmaf(m3a, q.y, av10);
    av11 = fmaf((float)vr[192+lane], m2b, av11); av11 = fmaf(m3b, q.y, av11);
    av20 = fmaf((float)vr[256+lane], m2a, av20); av20 = fmaf(m3a, q.z, av20);
    av21 = fmaf((float)vr[320+lane], m2b, av21); av21 = fmaf(m3b, q.z, av21);
  }
  float* dxr = dx + (size_t)n*128;
  dxr[lane] = ax0; dxr[64+lane] = ax1;
  float* dvr = dvec + (size_t)n*384;
  dvr[lane]     = av00 * INV_SQRT_Hf;
  dvr[64+lane]  = av01 * INV_SQRT_Hf;
  dvr[128+lane] = av10 * INV_SQRT_Hf;
  dvr[192+lane] = av11 * INV_SQRT_Hf;
  dvr[256+lane] = av20 * INV_SQRT_Hf;
  dvr[320+lane] = av21 * INV_SQRT_Hf;
}

// ---------------- node update (MFMA, 32 nodes/block) ----------------
__global__ __launch_bounds__(256) void k_node_mfma(
    float* __restrict__ xbuf, float* __restrict__ vbuf,
    const float* __restrict__ dx, const float* __restrict__ dvec,
    const _Float16* __restrict__ wfvp,
    const _Float16* __restrict__ wfxv1, const float* __restrict__ xv1_b,
    const _Float16* __restrict__ wfxv2, const float* __restrict__ xv2_b,
    _Float16* __restrict__ vec16)
{
  __shared__ _Float16 sV1[96][136];
  __shared__ _Float16 sCat[32][264];
  __shared__ _Float16 sVD[32][128];
  int t = threadIdx.x;
  int n0 = blockIdx.x * 32;
  int lane = t & 63, w = t >> 6, ml = lane & 15, kg = lane >> 4;
  int mt = w & 1, nbb = (w >> 1) * 4;
  float vd[4][4], vn[4][4];
  #pragma unroll
  for (int i=0;i<4;i++){
    #pragma unroll
    for (int r=0;r<4;r++){ vd[i][r]=0.f; vn[i][r]=0.f; }
  }
  int arow = n0 + mt*16 + ml;
  bool aok = arow < NN;
  for (int cd = 0; cd < 3; cd++){
    half8 a[4];
    #pragma unroll
    for (int ks = 0; ks < 4; ks++){
      if (aok){
        const float* vr = vbuf + (size_t)arow*384 + cd*128 + ks*32 + kg*8;
        const float* dr = dvec + (size_t)arow*384 + cd*128 + ks*32 + kg*8;
        float4 q0 = *(const float4*)(vr);
        float4 q1 = *(const float4*)(vr+4);
        float4 d0 = *(const float4*)(dr);
        float4 d1 = *(const float4*)(dr+4);
        a[ks][0]=(_Float16)(q0.x+d0.x); a[ks][1]=(_Float16)(q0.y+d0.y);
        a[ks][2]=(_Float16)(q0.z+d0.z); a[ks][3]=(_Float16)(q0.w+d0.w);
        a[ks][4]=(_Float16)(q1.x+d1.x); a[ks][5]=(_Float16)(q1.y+d1.y);
        a[ks][6]=(_Float16)(q1.z+d1.z); a[ks][7]=(_Float16)(q1.w+d1.w);
      } else {
        #pragma unroll
        for (int j=0;j<8;j++) a[ks][j] = (_Float16)0.f;
      }
    }
    #pragma unroll
    for (int nb4 = 0; nb4 < 4; nb4++){
      int nb1 = nbb + nb4;
      f32x4 acc1 = {0.f,0.f,0.f,0.f}, acc2 = {0.f,0.f,0.f,0.f};
      #pragma unroll
      for (int ks = 0; ks < 4; ks++){
        acc1 = __builtin_amdgcn_mfma_f32_16x16x32_f16(a[ks],
                 *(const half8*)(wfvp + ((size_t)(nb1*4+ks)*64 + lane)*8), acc1, 0,0,0);
        acc2 = __builtin_amdgcn_mfma_f32_16x16x32_f16(a[ks],
                 *(const half8*)(wfvp + ((size_t)((nb1+8)*4+ks)*64 + lane)*8), acc2, 0,0,0);
      }
      #pragma unroll
      for (int r = 0; r < 4; r++){
        float v1v = acc1[r], v2v = acc2[r];
        vd[nb4][r] += v1v*v2v;
        vn[nb4][r] += v2v*v2v;
        sV1[cd*32 + mt*16 + kg*4 + r][nb1*16 + ml] = (_Float16)v1v;
      }
    }
  }
  #pragma unroll
  for (int nb4 = 0; nb4 < 4; nb4++){
    #pragma unroll
    for (int r = 0; r < 4; r++){
      int m = mt*16 + kg*4 + r, c = (nbb+nb4)*16 + ml;
      sVD[m][c] = (_Float16)(vd[nb4][r] * INV_SQRT_Hf);
      sCat[m][128 + c] = (_Float16)sqrtf(vn[nb4][r] + 1e-8f);
    }
  }
  {
    int nd = t >> 3, sb = t & 7;
    int node = n0 + nd;
    if (node < NN){
      const float* xr = xbuf + (size_t)node*128 + sb*16;
      const float* dr = dx   + (size_t)node*128 + sb*16;
      #pragma unroll
      for (int g = 0; g < 4; g++){
        float4 qa = *(const float4*)(xr + g*4);
        float4 qb = *(const float4*)(dr + g*4);
        sCat[nd][sb*16+g*4+0] = (_Float16)((qa.x+qb.x)*INV_SQRT_2f);
        sCat[nd][sb*16+g*4+1] = (_Float16)((qa.y+qb.y)*INV_SQRT_2f);
        sCat[nd][sb*16+g*4+2] = (_Float16)((qa.z+qb.z)*INV_SQRT_2f);
        sCat[nd][sb*16+g*4+3] = (_Float16)((qa.w+qb.w)*INV_SQRT_2f);
      }
    } else {
      #pragma unroll
      for (int u = 0; u < 16; u++) sCat[nd][sb*16+u] = (_Float16)0.f;
    }
  }
  __syncthreads();
  float hreg[4][4];
  {
    half8 a[8];
    #pragma unroll
    for (int ks = 0; ks < 8; ks++)
      a[ks] = *(const half8*)&sCat[mt*16 + ml][ks*32 + kg*8];
    #pragma unroll
    for (int nb4 = 0; nb4 < 4; nb4++){
      int nb = (w>>1)*4 + nb4;
      float bias = xv1_b[nb*16 + ml];
      f32x4 acc = {bias, bias, bias, bias};
      #pragma unroll
      for (int ks = 0; ks < 8; ks++)
        acc = __builtin_amdgcn_mfma_f32_16x16x32_f16(a[ks],
                *(const half8*)(wfxv1 + ((size_t)(nb*8+ks)*64 + lane)*8), acc, 0,0,0);
      #pragma unroll
      for (int r = 0; r < 4; r++) hreg[nb4][r] = ssilu_f(acc[r]);
    }
  }
  __syncthreads();
  #pragma unroll
  for (int nb4 = 0; nb4 < 4; nb4++){
    int nb = (w>>1)*4 + nb4;
    #pragma unroll
    for (int r = 0; r < 4; r++)
      sCat[mt*16 + kg*4 + r][nb*16 + ml] = (_Float16)hreg[nb4][r];
  }
  __syncthreads();
  {
    half8 a[4];
    #pragma unroll
    for (int ks = 0; ks < 4; ks++)
      a[ks] = *(const half8*)&sCat[mt*16 + ml][ks*32 + kg*8];
    #pragma unroll 2
    for (int nb4 = 0; nb4 < 4; nb4++){
      int nbu = nbb + nb4;
      float b1v = xv2_b[nbu*16 + ml];
      float b2v = xv2_b[(nbu+8)*16 + ml];
      float b3v = xv2_b[(nbu+16)*16 + ml];
      f32x4 au1 = {b1v,b1v,b1v,b1v};
      f32x4 au2 = {b2v,b2v,b2v,b2v};
      f32x4 au3 = {b3v,b3v,b3v,b3v};
      #pragma unroll
      for (int ks = 0; ks < 4; ks++){
        au1 = __builtin_amdgcn_mfma_f32_16x16x32_f16(a[ks],
                *(const half8*)(wfxv2 + ((size_t)(nbu*4+ks)*64 + lane)*8), au1, 0,0,0);
        au2 = __builtin_amdgcn_mfma_f32_16x16x32_f16(a[ks],
                *(const half8*)(wfxv2 + ((size_t)((nbu+8)*4+ks)*64 + lane)*8), au2, 0,0,0);
        au3 = __builtin_amdgcn_mfma_f32_16x16x32_f16(a[ks],
                *(const half8*)(wfxv2 + ((size_t)((nbu+16)*4+ks)*64 + lane)*8), au3, 0,0,0);
      }
      #pragma unroll
      for (int r = 0; r < 4; r++){
        int m = mt*16 + kg*4 + r;
        int node = n0 + m;
        if (node >= NN) continue;
        int c = nbu*16 + ml;
        float xu1 = au1[r], xu2 = au2[r], xu3 = au3[r];
        float vdv = (float)sVD[m][c];
        size_t px = (size_t)node*128 + c;
        float xn = (xbuf[px] + dx[px]) * INV_SQRT_2f;
        xbuf[px] = xn + (xu1 + xu2*vdv) * INV_SQRT_2f;
        #pragma unroll
        for (int cd = 0; cd < 3; cd++){
          float v1v = (float)sV1[cd*32 + m][c];
          size_t pv = (size_t)node*384 + cd*128 + c;
          float vo = vbuf[pv] + dvec[pv] + xu3*v1v;
          vbuf[pv] = vo;
          vec16[pv] = (_Float16)vo;
        }
      }
    }
  }
}

// ---------------- merged final: energy + gated block 1 + gated block 2 (32 nodes/block) ----------------
__global__ __launch_bounds__(256) void k_final(
    const float* __restrict__ x, const float* __restrict__ vec,
    const _Float16* __restrict__ wfin,
    const float* __restrict__ be1, const float* __restrict__ we2, const float* __restrict__ be2,
    const float* __restrict__ u1b, const float* __restrict__ u2b,
    const float* __restrict__ g2v2, const float* __restrict__ g2u1b, const float* __restrict__ g2u2,
    const float* __restrict__ g2u2b,
    float* __restrict__ out)
{
  __shared__ _Float16 sCat[32][264];  // x | n1 ; later fx | n1g2
  __shared__ _Float16 sV2[3][32][72];
  __shared__ _Float16 sH[32][136];
  __shared__ _Float16 sFV[3][32][72];
  __shared__ _Float16 sE1[32][72];    // e1; later hg2
  __shared__ float sR[3][32];
  int t = threadIdx.x;
  int n0 = blockIdx.x * 32;
  int lane = t & 63, w = t >> 6, ml = lane & 15, kg = lane >> 4;
  int mt = w & 1, nh = w >> 1;

  // stage x -> sCat[:,0:128)
  {
    int nd = t >> 3, sb = t & 7;
    int node = n0 + nd;
    if (node < NN){
      const float* xr = x + (size_t)node*128 + sb*16;
      #pragma unroll
      for (int g = 0; g < 4; g++){
        float4 q = *(const float4*)(xr + g*4);
        sCat[nd][sb*16+g*4+0]=(_Float16)q.x; sCat[nd][sb*16+g*4+1]=(_Float16)q.y;
        sCat[nd][sb*16+g*4+2]=(_Float16)q.z; sCat[nd][sb*16+g*4+3]=(_Float16)q.w;
      }
    } else {
      #pragma unroll
      for (int u = 0; u < 16; u++) sCat[nd][sb*16+u] = (_Float16)0.f;
    }
  }
  // vp GEMMs from vec (global): wv1 -> n1, wv2 -> sV2
  {
    int arow = n0 + mt*16 + ml;
    bool aok = arow < NN;
    float n1sq[4][4];
    #pragma unroll
    for (int i=0;i<4;i++){
      #pragma unroll
      for (int r=0;r<4;r++) n1sq[i][r]=0.f;
    }
    for (int cd = 0; cd < 3; cd++){
      half8 a[4];
      #pragma unroll
      for (int ks = 0; ks < 4; ks++){
        if (aok){
          const float* vr = vec + (size_t)arow*384 + cd*128 + ks*32 + kg*8;
          float4 q0 = *(const float4*)(vr);
          float4 q1 = *(const float4*)(vr+4);
          a[ks][0]=(_Float16)q0.x; a[ks][1]=(_Float16)q0.y; a[ks][2]=(_Float16)q0.z; a[ks][3]=(_Float16)q0.w;
          a[ks][4]=(_Float16)q1.x; a[ks][5]=(_Float16)q1.y; a[ks][6]=(_Float16)q1.z; a[ks][7]=(_Float16)q1.w;
        } else {
          #pragma unroll
          for (int j=0;j<8;j++) a[ks][j] = (_Float16)0.f;
        }
      }
      #pragma unroll
      for (int nb4 = 0; nb4 < 4; nb4++){
        int nb = nh*4 + nb4;
        f32x4 acc = {0.f,0.f,0.f,0.f};
        #pragma unroll
        for (int ks = 0; ks < 4; ks++)
          acc = __builtin_amdgcn_mfma_f32_16x16x32_f16(a[ks],
                  *(const half8*)(wfin + WV1OFF + ((size_t)(nb*4+ks)*64 + lane)*8), acc, 0,0,0);
        #pragma unroll
        for (int r = 0; r < 4; r++) n1sq[nb4][r] += acc[r]*acc[r];
      }
      #pragma unroll
      for (int q = 0; q < 2; q++){
        int nb = nh*2 + q;
        f32x4 acc = {0.f,0.f,0.f,0.f};
        #pragma unroll
        for (int ks = 0; ks < 4; ks++)
          acc = __builtin_amdgcn_mfma_f32_16x16x32_f16(a[ks],
                  *(const half8*)(wfin + WV2OFF + ((size_t)(nb*4+ks)*64 + lane)*8), acc, 0,0,0);
        #pragma unroll
        for (int r = 0; r < 4; r++)
          sV2[cd][mt*16 + kg*4 + r][nb*16 + ml] = (_Float16)acc[r];
      }
    }
    #pragma unroll
    for (int nb4 = 0; nb4 < 4; nb4++){
      #pragma unroll
      for (int r = 0; r < 4; r++)
        sCat[mt*16 + kg*4 + r][128 + nh*64 + nb4*16 + ml] = (_Float16)sqrtf(n1sq[nb4][r]);
    }
  }
  __syncthreads();
  // e1 = ssilu(x@we1+be1); h = ssilu(cat(x,n1)@wu1+u1b)
  {
    half8 a[8];
    #pragma unroll
    for (int ks = 0; ks < 8; ks++)
      a[ks] = *(const half8*)&sCat[mt*16 + ml][ks*32 + kg*8];
    #pragma unroll
    for (int q = 0; q < 2; q++){
      int nb = nh*2 + q;
      float bias = be1[nb*16 + ml];
      f32x4 acc = {bias, bias, bias, bias};
      #pragma unroll
      for (int ks = 0; ks < 4; ks++)
        acc = __builtin_amdgcn_mfma_f32_16x16x32_f16(a[ks],
                *(const half8*)(wfin + WE1OFF + ((size_t)(nb*4+ks)*64 + lane)*8), acc, 0,0,0);
      #pragma unroll
      for (int r = 0; r < 4; r++)
        sE1[mt*16 + kg*4 + r][nb*16 + ml] = (_Float16)ssilu_f(acc[r]);
    }
    #pragma unroll
    for (int nb4 = 0; nb4 < 4; nb4++){
      int nb = nh*4 + nb4;
      float bias = u1b[nb*16 + ml];
      f32x4 acc = {bias, bias, bias, bias};
      #pragma unroll
      for (int ks = 0; ks < 8; ks++)
        acc = __builtin_amdgcn_mfma_f32_16x16x32_f16(a[ks],
                *(const half8*)(wfin + WU1OFF + ((size_t)(nb*8+ks)*64 + lane)*8), acc, 0,0,0);
      #pragma unroll
      for (int r = 0; r < 4; r++)
        sH[mt*16 + kg*4 + r][nb*16 + ml] = (_Float16)ssilu_f(acc[r]);
    }
  }
  __syncthreads();
  // h2 = h@wu2+u2b -> fx (c<64, into sCat[:,0:64)) / fv (c>=64, into sFV); energy reduce
  {
    half8 a[4];
    #pragma unroll
    for (int ks = 0; ks < 4; ks++)
      a[ks] = *(const half8*)&sH[mt*16 + ml][ks*32 + kg*8];
    #pragma unroll
    for (int nb4 = 0; nb4 < 4; nb4++){
      int nb = nh*4 + nb4;
      float bias = u2b[nb*16 + ml];
      f32x4 acc = {bias, bias, bias, bias};
      #pragma unroll
      for (int ks = 0; ks < 4; ks++)
        acc = __builtin_amdgcn_mfma_f32_16x16x32_f16(a[ks],
                *(const half8*)(wfin + WU2OFF + ((size_t)(nb*4+ks)*64 + lane)*8), acc, 0,0,0);
      int c = nb*16 + ml;
      #pragma unroll
      for (int r = 0; r < 4; r++){
        int m = mt*16 + kg*4 + r;
        if (c < 64){
          sCat[m][c] = (_Float16)ssilu_f(acc[r]);
        } else {
          float xv = acc[r];
          #pragma unroll
          for (int cd = 0; cd < 3; cd++)
            sFV[cd][m][c-64] = (_Float16)(xv * (float)sV2[cd][m][c-64]);
        }
      }
    }
    // energy: e1 . we2
    float wev = we2[lane];
    #pragma unroll
    for (int i = 0; i < 8; i++){
      int nd = w*8 + i;
      float v = (float)sE1[nd][lane] * wev;
      #pragma unroll
      for (int o2 = 32; o2 > 0; o2 >>= 1) v += __shfl_xor(v, o2, 64);
      int node = n0 + nd;
      if (lane == 0 && node < NN) out[(size_t)node*4 + 0] = v + be2[0];
    }
  }
  __syncthreads();
  // g2: a = fv@g2v1 -> n1g2 (into sCat[:,64:128)); r = fv.g2v2 -> sR
  {
    float n1sq[2][4];
    #pragma unroll
    for (int q=0;q<2;q++){
      #pragma unroll
      for (int r=0;r<4;r++) n1sq[q][r]=0.f;
    }
    for (int cd = 0; cd < 3; cd++){
      half8 a[2];
      #pragma unroll
      for (int ks = 0; ks < 2; ks++)
        a[ks] = *(const half8*)&sFV[cd][mt*16 + ml][ks*32 + kg*8];
      #pragma unroll
      for (int q = 0; q < 2; q++){
        int nb = nh*2 + q;
        f32x4 acc = {0.f,0.f,0.f,0.f};
        #pragma unroll
        for (int ks = 0; ks < 2; ks++)
          acc = __builtin_amdgcn_mfma_f32_16x16x32_f16(a[ks],
                  *(const half8*)(wfin + G2V1OFF + ((size_t)(nb*2+ks)*64 + lane)*8), acc, 0,0,0);
        #pragma unroll
        for (int r = 0; r < 4; r++) n1sq[q][r] += acc[r]*acc[r];
      }
    }
    #pragma unroll
    for (int q = 0; q < 2; q++){
      #pragma unroll
      for (int r = 0; r < 4; r++)
        sCat[mt*16 + kg*4 + r][64 + (nh*2+q)*16 + ml] = (_Float16)sqrtf(n1sq[q][r]);
    }
    float g2v = g2v2[lane];
    #pragma unroll
    for (int i = 0; i < 8; i++){
      int nd = w*8 + i;
      #pragma unroll
      for (int cd = 0; cd < 3; cd++){
        float v = (float)sFV[cd][nd][lane] * g2v;
        #pragma unroll
        for (int o2 = 32; o2 > 0; o2 >>= 1) v += __shfl_xor(v, o2, 64);
        if (lane == 0) sR[cd][nd] = v;
      }
    }
  }
  __syncthreads();
  // hg2 = ssilu(cat(fx,n1g2)@g2u1+g2u1b) -> sE1
  {
    half8 a[4];
    #pragma unroll
    for (int ks = 0; ks < 4; ks++)
      a[ks] = *(const half8*)&sCat[mt*16 + ml][ks*32 + kg*8];
    #pragma unroll
    for (int q = 0; q < 2; q++){
      int nb = nh*2 + q;
      float bias = g2u1b[nb*16 + ml];
      f32x4 acc = {bias, bias, bias, bias};
      #pragma unroll
      for (int ks = 0; ks < 4; ks++)
        acc = __builtin_amdgcn_mfma_f32_16x16x32_f16(a[ks],
                *(const half8*)(wfin + G2U1OFF + ((size_t)(nb*4+ks)*64 + lane)*8), acc, 0,0,0);
      #pragma unroll
      for (int r = 0; r < 4; r++)
        sE1[mt*16 + kg*4 + r][nb*16 + ml] = (_Float16)ssilu_f(acc[r]);
    }
  }
  __syncthreads();
  // s1 = hg2 . g2u2[:,1]; forces
  {
    float g2w = g2u2[lane*2 + 1];
    #pragma unroll
    for (int i = 0; i < 8; i++){
      int nd = w*8 + i;
      float v = (float)sE1[nd][lane] * g2w;
      #pragma unroll
      for (int o2 = 32; o2 > 0; o2 >>= 1) v += __shfl_xor(v, o2, 64);
      int node = n0 + nd;
      if (lane == 0 && node < NN){
        float h21 = v + g2u2b[1];
        out[(size_t)node*4 + 1] = h21 * sR[0][nd];
        out[(size_t)node*4 + 2] = h21 * sR[1][nd];
        out[(size_t)node*4 + 3] = h21 * sR[2][nd];
      }
    }
  }
}

extern "C" void kernel_launch(void* const* d_in, const int* in_sizes, int n_in,
                              void* d_out, int out_size, void* d_ws, size_t ws_size,
                              hipStream_t stream)
{
  const float* x_in   = (const float*)d_in[0];
  const float* vec_in = (const float*)d_in[1];
  const int*   eidx   = (const int*)d_in[2];
  const float* erbf   = (const float*)d_in[3];
  const float* evec   = (const float*)d_in[4];
  const float* ln_w  = (const float*)d_in[5];
  const float* ln_b  = (const float*)d_in[6];
  const float* xp1_w = (const float*)d_in[7];
  const float* xp1_b = (const float*)d_in[8];
  const float* xp2_w = (const float*)d_in[9];
  const float* xp2_b = (const float*)d_in[10];
  const float* rbf_w = (const float*)d_in[11];
  const float* rbf_b = (const float*)d_in[12];
  const float* vp_w  = (const float*)d_in[13];
  const float* xv1_w = (const float*)d_in[14];
  const float* xv1_b = (const float*)d_in[15];
  const float* xv2_w = (const float*)d_in[16];
  const float* xv2_b = (const float*)d_in[17];
  const float* we1 = (const float*)d_in[18];
  const float* be1 = (const float*)d_in[19];
  const float* we2 = (const float*)d_in[20];
  const float* be2 = (const float*)d_in[21];
  const float* g1_v1 = (const float*)d_in[22];
  const float* g1_v2 = (const float*)d_in[23];
  const float* g1_u1 = (const float*)d_in[24];
  const float* g1_u1b = (const float*)d_in[25];
  const float* g1_u2 = (const float*)d_in[26];
  const float* g1_u2b = (const float*)d_in[27];
  const float* g2_v1 = (const float*)d_in[28];
  const float* g2_v2 = (const float*)d_in[29];
  const float* g2_u1 = (const float*)d_in[30];
  const float* g2_u1b = (const float*)d_in[31];
  const float* g2_u2 = (const float*)d_in[32];
  const float* g2_u2b = (const float*)d_in[33];
  float* out = (float*)d_out;

  char* base = (char*)d_ws;
  size_t o = 0;
  auto alloc = [&](size_t bytes) -> char* {
    char* p = base + o;
    o = (o + bytes + 255) & ~(size_t)255;
    return p;
  };
  float* x_cur   = (float*)alloc((size_t)NN*128*4);
  float* vec_cur = (float*)alloc((size_t)NN*384*4);
  float* dx      = (float*)alloc((size_t)NN*128*4);
  float* dvec    = (float*)alloc((size_t)NN*384*4);
  _Float16* xh16 = (_Float16*)alloc((size_t)NN*384*2);
  _Float16* vec16= (_Float16*)alloc((size_t)NN*384*2);
  int*   eord    = (int*)alloc((size_t)EE*4);
  int*   off     = (int*)alloc((size_t)(NN+1)*4);
  _Float16* wf   = (_Float16*)alloc((size_t)LL*24576*2);
  float* bsc     = (float*)alloc((size_t)LL*384*4);
  _Float16* wfn  = (_Float16*)alloc((size_t)LL*180224*2);
  _Float16* wfin = (_Float16*)alloc((size_t)WFIN_SZ*2);
  _Float16* eA   = (_Float16*)alloc((size_t)EE*64*2);
  float4* es4    = (float4*)alloc((size_t)EE*16);
  _Float16* rbfh = (_Float16*)alloc((size_t)EE*384*2);
  int* cnt = (int*)dx;  // pre-layer-0 reuse
  int* cur = cnt + NN;

  hipMemcpyAsync(x_cur, x_in, sizeof(float)*(size_t)NN*128, hipMemcpyDeviceToDevice, stream);
  hipMemcpyAsync(vec_cur, vec_in, sizeof(float)*(size_t)NN*384, hipMemcpyDeviceToDevice, stream);

  const int* esrc = eidx;
  const int* edst = eidx + EE;

  hipMemsetAsync(cnt, 0, sizeof(int)*NN, stream);
  k_hist<<<(EE+255)/256, 256, 0, stream>>>(edst, cnt);
  k_scan<<<1, 1024, 0, stream>>>(cnt, off, cur);
  k_fill<<<(EE+255)/256, 256, 0, stream>>>(edst, cur, eord);
  k_sorta<<<(EE*64+255)/256, 256, 0, stream>>>(erbf, eord, eA);
  k_sorte<<<(EE+255)/256, 256, 0, stream>>>(esrc, evec, eord, es4);
  k_packw<<<(LL*24576+255)/256, 256, 0, stream>>>(rbf_w, wf);
  k_packb<<<(LL*384+255)/256, 256, 0, stream>>>(rbf_b, bsc);
  k_cvt16<<<(NN*384+255)/256, 256, 0, stream>>>(vec_in, vec16, NN*384);

  {
    PackTab tb;
    for (int l = 0; l < LL; l++){
      _Float16* wb = wfn + (size_t)l*180224;
      tb.s[l*5+0] = xp1_w + (size_t)l*128*128; tb.d[l*5+0] = wb;          tb.K[l*5+0]=128; tb.NO[l*5+0]=128;
      tb.s[l*5+1] = xp2_w + (size_t)l*128*384; tb.d[l*5+1] = wb+16384;    tb.K[l*5+1]=128; tb.NO[l*5+1]=384;
      tb.s[l*5+2] = vp_w  + (size_t)l*128*256; tb.d[l*5+2] = wb+65536;    tb.K[l*5+2]=128; tb.NO[l*5+2]=256;
      tb.s[l*5+3] = xv1_w + (size_t)l*256*128; tb.d[l*5+3] = wb+98304;    tb.K[l*5+3]=256; tb.NO[l*5+3]=128;
      tb.s[l*5+4] = xv2_w + (size_t)l*128*384; tb.d[l*5+4] = wb+131072;   tb.K[l*5+4]=128; tb.NO[l*5+4]=384;
    }
    tb.s[30] = we1;   tb.d[30] = wfin + WE1OFF;  tb.K[30]=128; tb.NO[30]=64;
    tb.s[31] = g1_v1; tb.d[31] = wfin + WV1OFF;  tb.K[31]=128; tb.NO[31]=128;
    tb.s[32] = g1_v2; tb.d[32] = wfin + WV2OFF;  tb.K[32]=128; tb.NO[32]=64;
    tb.s[33] = g1_u1; tb.d[33] = wfin + WU1OFF;  tb.K[33]=256; tb.NO[33]=128;
    tb.s[34] = g1_u2; tb.d[34] = wfin + WU2OFF;  tb.K[34]=128; tb.NO[34]=128;
    tb.s[35] = g2_v1; tb.d[35] = wfin + G2V1OFF; tb.K[35]=64;  tb.NO[35]=64;
    tb.s[36] = g2_u1; tb.d[36] = wfin + G2U1OFF; tb.K[36]=128; tb.NO[36]=64;
    k_packall<<<dim3(24, 37), 256, 0, stream>>>(tb);
  }

  for (int l = 0; l < LL; l++){
    _Float16* wb = wfn + (size_t)l*180224;
    k_xh_mfma<<<(NN+31)/32, 256, 0, stream>>>(x_cur, ln_w + l*128, ln_b + l*128,
        wb, xp1_b + l*128, wb+16384, xp2_b + l*384, xh16);
    k_gemm_rbfh<<<EE/64, 64, 0, stream>>>(eA, wf + (size_t)l*24576,
        bsc + (size_t)l*384, rbfh);
    k_edge3<<<NN/4, 256, 0, stream>>>(rbfh, es4, off, xh16, vec16, dx, dvec);
    k_node_mfma<<<(NN+31)/32, 256, 0, stream>>>(x_cur, vec_cur, dx, dvec,
        wb+65536, wb+98304, xv1_b + l*128, wb+131072, xv2_b + l*384, vec16);
  }
  k_final<<<(NN+31)/32, 256, 0, stream>>>(x_cur, vec_cur, wfin,
      be1, we2, be2, g1_u1b, g1_u2b, g2_v2, g2_u1b, g2_u2, g2_u2b, out);
}